// Round 1
// baseline (650.513 us; speedup 1.0000x reference)
//
#include <hip/hip_runtime.h>
#include <hip/hip_bf16.h>
#include <math.h>

#define NB 32768      // total nodes (B*N)
#define NN 2048       // nodes per graph
#define BG 16         // graphs
#define KK 1639       // kept per graph
#define N1 (BG*KK)    // 26224 kept nodes total
#define EE 524288     // total edges
#define HH 128        // hidden
#define FIN 64        // input features
#define SLICES 16

// ---------------- CSR build ----------------
__global__ void deg_kernel(const int* __restrict__ dst, int* deg, int n) {
  int e = blockIdx.x * blockDim.x + threadIdx.x;
  if (e < n) atomicAdd(&deg[dst[e]], 1);
}

__global__ void deg2_kernel(const int* __restrict__ src, const int* __restrict__ dst,
                            const int* __restrict__ new_id, int* deg, int n) {
  int e = blockIdx.x * blockDim.x + threadIdx.x;
  if (e < n) {
    int a = new_id[src[e]], d = new_id[dst[e]];
    if (a >= 0 && d >= 0) atomicAdd(&deg[d], 1);
  }
}

// single-block exclusive scan over n entries; writes rs[0..n] and cursor[0..n-1]=rs
__global__ void exscan_kernel(const int* __restrict__ deg, int* rs, int* cursor, int n) {
  __shared__ int sd[1024];
  int tid = threadIdx.x;
  int running = 0;
  for (int base = 0; base < n; base += 1024) {
    int idx = base + tid;
    int v = (idx < n) ? deg[idx] : 0;
    sd[tid] = v;
    __syncthreads();
    for (int off = 1; off < 1024; off <<= 1) {
      int t = (tid >= off) ? sd[tid - off] : 0;
      __syncthreads();
      sd[tid] += t;
      __syncthreads();
    }
    int inc = sd[tid];
    int total = sd[1023];
    if (idx < n) { int ex = running + inc - v; rs[idx] = ex; cursor[idx] = ex; }
    running += total;
    __syncthreads();
  }
  if (tid == 0) rs[n] = running;
}

__global__ void scatter_kernel(const int* __restrict__ src, const int* __restrict__ dst,
                               int* cursor, int* csr, int n) {
  int e = blockIdx.x * blockDim.x + threadIdx.x;
  if (e < n) {
    int d = dst[e];
    int p = atomicAdd(&cursor[d], 1);
    csr[p] = src[e];
  }
}

__global__ void scatter2_kernel(const int* __restrict__ src, const int* __restrict__ dst,
                                const int* __restrict__ new_id, int* cursor, int* csr, int n) {
  int e = blockIdx.x * blockDim.x + threadIdx.x;
  if (e < n) {
    int a = new_id[src[e]], d = new_id[dst[e]];
    if (a >= 0 && d >= 0) {
      int p = atomicAdd(&cursor[d], 1);
      csr[p] = a;
    }
  }
}

// ---------------- aggregation (gather-sum) ----------------
// blockDim.x == F (64 or 128); one block per destination node
__global__ void agg_kernel(const float* __restrict__ feat, int ldf,
                           const int* __restrict__ rs, const int* __restrict__ csr,
                           float* agg, int M) {
  int i = blockIdx.x;
  if (i >= M) return;
  int f = threadIdx.x;
  int e0 = rs[i], e1 = rs[i + 1];
  float acc = 0.f;
  for (int e = e0; e < e1; ++e) acc += feat[csr[e] * ldf + f];
  agg[i * HH + f] = acc;
}

// ---------------- fused conv matmul: relu(agg@WrelT + x@WrootT + b) ----------------
template <int KD>
__global__ void mm_kernel(const float* __restrict__ agg, const float* __restrict__ xr, int ldx,
                          const float* __restrict__ wrelT, const float* __restrict__ wrootT,
                          const float* __restrict__ bias, float* out, int M) {
  const int RPB = 8;
  __shared__ float sA[RPB][KD];
  __shared__ float sX[RPB][KD];
  int row0 = blockIdx.x * RPB;
  int tid = threadIdx.x;  // 128
  for (int idx = tid; idx < RPB * KD; idx += 128) {
    int r = idx / KD, f = idx % KD;
    int row = row0 + r;
    sA[r][f] = (row < M) ? agg[row * HH + f] : 0.f;
    sX[r][f] = (row < M) ? xr[row * ldx + f] : 0.f;
  }
  __syncthreads();
  int o = tid;
  float bv = bias[o];
  float acc[RPB];
#pragma unroll
  for (int r = 0; r < RPB; ++r) acc[r] = bv;
  for (int f = 0; f < KD; ++f) {
    float w1 = wrelT[f * HH + o];
    float w2 = wrootT[f * HH + o];
#pragma unroll
    for (int r = 0; r < RPB; ++r) acc[r] = fmaf(sA[r][f], w1, fmaf(sX[r][f], w2, acc[r]));
  }
#pragma unroll
  for (int r = 0; r < RPB; ++r) {
    int row = row0 + r;
    if (row < M) out[row * HH + o] = fmaxf(acc[r], 0.f);
  }
}

// ---------------- weight transpose ----------------
__global__ void transpose_kernel(const float* __restrict__ W, float* WT, int O, int KDv) {
  int idx = blockIdx.x * blockDim.x + threadIdx.x;
  if (idx < O * KDv) {
    int o = idx / KDv, f = idx % KDv;
    WT[f * O + o] = W[idx];
  }
}

// ---------------- pooling ----------------
__global__ void pool_partial_kernel(const float* __restrict__ h, int rows_per_graph,
                                    float* pmax, float* psum) {
  int b = blockIdx.x / SLICES, s = blockIdx.x % SLICES;
  int f = threadIdx.x;
  int per = (rows_per_graph + SLICES - 1) / SLICES;
  int r0 = s * per, r1 = min(rows_per_graph, r0 + per);
  float m = -3.402823466e38f, sum = 0.f;
  for (int r = r0; r < r1; ++r) {
    float v = h[(size_t)(b * rows_per_graph + r) * HH + f];
    m = fmaxf(m, v);
    sum += v;
  }
  pmax[(b * SLICES + s) * HH + f] = m;
  psum[(b * SLICES + s) * HH + f] = sum;
}

__global__ void pool_final_kernel(const float* __restrict__ pmax, const float* __restrict__ psum,
                                  float* x, float inv_count) {
  int b = blockIdx.x;
  int f = threadIdx.x;
  float m = -3.402823466e38f, s = 0.f;
  for (int s2 = 0; s2 < SLICES; ++s2) {
    m = fmaxf(m, pmax[(b * SLICES + s2) * HH + f]);
    s += psum[(b * SLICES + s2) * HH + f];
  }
  x[b * 256 + f] = m;
  x[b * 256 + 128 + f] = s * inv_count;
}

// ---------------- scoring / topk ----------------
__global__ void norm_kernel(const float* __restrict__ w, float* normv) {
  __shared__ float sd[128];
  int t = threadIdx.x;
  sd[t] = w[t] * w[t];
  __syncthreads();
  for (int off = 64; off > 0; off >>= 1) {
    if (t < off) sd[t] += sd[t + off];
    __syncthreads();
  }
  if (t == 0) normv[0] = sqrtf(sd[0]);
}

__global__ void score_kernel(const float* __restrict__ h2, const float* __restrict__ w,
                             const float* __restrict__ normv, float* score, int M) {
  int wave = threadIdx.x >> 6;
  int lane = threadIdx.x & 63;
  int i = blockIdx.x * (blockDim.x >> 6) + wave;
  if (i >= M) return;
  float acc = h2[i * HH + lane] * w[lane] + h2[i * HH + 64 + lane] * w[64 + lane];
  for (int off = 32; off > 0; off >>= 1) acc += __shfl_down(acc, off, 64);
  if (lane == 0) score[i] = tanhf(acc / normv[0]);
}

// per-graph bitonic sort of 2048 (score,index) keys; keep top K, tie-break lowest index
__global__ void topk_kernel(const float* __restrict__ score, int* perm) {
  __shared__ unsigned long long k[NN];
  int b = blockIdx.x;
  int tid = threadIdx.x;  // 1024
  for (int i = tid; i < NN; i += 1024) {
    float s = score[b * NN + i];
    unsigned u = __float_as_uint(s);
    u = (u & 0x80000000u) ? ~u : (u | 0x80000000u);
    unsigned long long key = ((unsigned long long)u << 32) | (unsigned)(NN - 1 - i);
    k[i] = ~key;  // ascending sort of ~key == descending by (score, -index)
  }
  __syncthreads();
  for (int kk = 2; kk <= NN; kk <<= 1) {
    for (int j = kk >> 1; j > 0; j >>= 1) {
      for (int t = tid; t < NN; t += 1024) {
        int ixj = t ^ j;
        if (ixj > t) {
          bool up = ((t & kk) == 0);
          unsigned long long a = k[t], c = k[ixj];
          if ((a > c) == up) { k[t] = c; k[ixj] = a; }
        }
      }
      __syncthreads();
    }
  }
  for (int j = tid; j < KK; j += 1024) {
    unsigned long long key = ~k[j];
    int i = (NN - 1) - (int)(key & 0xffffffffu);
    perm[b * KK + j] = b * NN + i;
  }
}

__global__ void h3_kernel(const float* __restrict__ h2, const int* __restrict__ perm,
                          const float* __restrict__ score, float* h3) {
  int idx = blockIdx.x * blockDim.x + threadIdx.x;
  if (idx < N1 * HH) {
    int g = idx >> 7, f = idx & 127;
    int p = perm[g];
    h3[idx] = h2[p * HH + f] * score[p];
  }
}

__global__ void newid_kernel(const int* __restrict__ perm, int* new_id) {
  int g = blockIdx.x * blockDim.x + threadIdx.x;
  if (g < N1) new_id[perm[g]] = g;
}

// ---------------- final MLP ----------------
__global__ void mlp_kernel(const float* __restrict__ x1, const float* __restrict__ x2,
                           const float* __restrict__ x3,
                           const float* __restrict__ Wl1, const float* __restrict__ bl1,
                           const float* __restrict__ Wl2, const float* __restrict__ bl2,
                           const float* __restrict__ Wl3, const float* __restrict__ bl3,
                           float* out) {
  __shared__ float z[256], a1[128], a2[64], a3[10], red[2];
  int b = blockIdx.x, t = threadIdx.x;  // 128 threads
  for (int i = t; i < 256; i += 128) z[i] = x1[b * 256 + i] + x2[b * 256 + i] + x3[b * 256 + i];
  __syncthreads();
  {
    float acc = bl1[t];
    for (int q = 0; q < 256; ++q) acc = fmaf(Wl1[t * 256 + q], z[q], acc);
    a1[t] = fmaxf(acc, 0.f);
  }
  __syncthreads();
  if (t < 64) {
    float acc = bl2[t];
    for (int q = 0; q < 128; ++q) acc = fmaf(Wl2[t * 128 + q], a1[q], acc);
    a2[t] = fmaxf(acc, 0.f);
  }
  __syncthreads();
  if (t < 10) {
    float acc = bl3[t];
    for (int q = 0; q < 64; ++q) acc = fmaf(Wl3[t * 64 + q], a2[q], acc);
    a3[t] = acc;
  }
  __syncthreads();
  if (t == 0) {
    float m = a3[0];
    for (int i = 1; i < 10; ++i) m = fmaxf(m, a3[i]);
    float s = 0.f;
    for (int i = 0; i < 10; ++i) s += expf(a3[i] - m);
    red[0] = m;
    red[1] = logf(s);
  }
  __syncthreads();
  if (t < 10) out[b * 10 + t] = a3[t] - red[0] - red[1];
}

extern "C" void kernel_launch(void* const* d_in, const int* in_sizes, int n_in,
                              void* d_out, int out_size, void* d_ws, size_t ws_size,
                              hipStream_t stream) {
  const float* x       = (const float*)d_in[0];
  const int*   src     = (const int*)d_in[1];
  const int*   dst     = (const int*)d_in[2];
  const float* W1_rel  = (const float*)d_in[3];
  const float* b1      = (const float*)d_in[4];
  const float* W1_root = (const float*)d_in[5];
  const float* W2_rel  = (const float*)d_in[6];
  const float* b2      = (const float*)d_in[7];
  const float* W2_root = (const float*)d_in[8];
  const float* W3_rel  = (const float*)d_in[9];
  const float* b3      = (const float*)d_in[10];
  const float* W3_root = (const float*)d_in[11];
  const float* pool_w  = (const float*)d_in[12];
  const float* Wl1     = (const float*)d_in[13];
  const float* bl1     = (const float*)d_in[14];
  const float* Wl2     = (const float*)d_in[15];
  const float* bl2     = (const float*)d_in[16];
  const float* Wl3     = (const float*)d_in[17];
  const float* bl3     = (const float*)d_in[18];
  float* out = (float*)d_out;

  // workspace layout
  char* w = (char*)d_ws;
  size_t off = 0;
  auto alloc = [&](size_t bytes) -> char* {
    off = (off + 255) & ~(size_t)255;
    char* p = w + off;
    off += bytes;
    return p;
  };
  int* rs1      = (int*)alloc((NB + 1) * 4);
  int* cursor1  = (int*)alloc(NB * 4);
  int* deg1     = (int*)alloc(NB * 4);
  int* csr1     = (int*)alloc((size_t)EE * 4);
  int* rs2      = (int*)alloc((N1 + 1) * 4);
  int* cursor2  = (int*)alloc(N1 * 4);
  int* deg2     = (int*)alloc(N1 * 4);
  int* csr2     = (int*)alloc((size_t)EE * 4);
  int* new_id   = (int*)alloc(NB * 4);
  int* perm     = (int*)alloc(N1 * 4);
  float* w1relT  = (float*)alloc(64 * 128 * 4);
  float* w1rootT = (float*)alloc(64 * 128 * 4);
  float* w2relT  = (float*)alloc(128 * 128 * 4);
  float* w2rootT = (float*)alloc(128 * 128 * 4);
  float* w3relT  = (float*)alloc(128 * 128 * 4);
  float* w3rootT = (float*)alloc(128 * 128 * 4);
  float* agg  = (float*)alloc((size_t)NB * HH * 4);
  float* bufA = (float*)alloc((size_t)NB * HH * 4);  // h1 then h3
  float* bufB = (float*)alloc((size_t)NB * HH * 4);  // h2 then h4
  float* score = (float*)alloc(NB * 4);
  float* normv = (float*)alloc(64);
  float* pmax  = (float*)alloc(BG * SLICES * HH * 4);
  float* psum  = (float*)alloc(BG * SLICES * HH * 4);
  float* x1v   = (float*)alloc(BG * 256 * 4);
  float* x2v   = (float*)alloc(BG * 256 * 4);
  float* x3v   = (float*)alloc(BG * 256 * 4);
  if (off > ws_size) return;  // workspace too small: fail visibly (output stays zero)

  const int TB = 256;
  const int egrid = (EE + TB - 1) / TB;

  hipMemsetAsync(deg1, 0, NB * 4, stream);
  hipMemsetAsync(deg2, 0, N1 * 4, stream);
  hipMemsetAsync(new_id, 0xFF, NB * 4, stream);  // -1

  // transpose weights
  transpose_kernel<<<(128 * 64 + TB - 1) / TB, TB, 0, stream>>>(W1_rel, w1relT, 128, 64);
  transpose_kernel<<<(128 * 64 + TB - 1) / TB, TB, 0, stream>>>(W1_root, w1rootT, 128, 64);
  transpose_kernel<<<(128 * 128 + TB - 1) / TB, TB, 0, stream>>>(W2_rel, w2relT, 128, 128);
  transpose_kernel<<<(128 * 128 + TB - 1) / TB, TB, 0, stream>>>(W2_root, w2rootT, 128, 128);
  transpose_kernel<<<(128 * 128 + TB - 1) / TB, TB, 0, stream>>>(W3_rel, w3relT, 128, 128);
  transpose_kernel<<<(128 * 128 + TB - 1) / TB, TB, 0, stream>>>(W3_root, w3rootT, 128, 128);

  // CSR over (src -> dst)
  deg_kernel<<<egrid, TB, 0, stream>>>(dst, deg1, EE);
  exscan_kernel<<<1, 1024, 0, stream>>>(deg1, rs1, cursor1, NB);
  scatter_kernel<<<egrid, TB, 0, stream>>>(src, dst, cursor1, csr1, EE);

  // conv1
  agg_kernel<<<NB, 64, 0, stream>>>(x, FIN, rs1, csr1, agg, NB);
  mm_kernel<64><<<NB / 8, 128, 0, stream>>>(agg, x, FIN, w1relT, w1rootT, b1, bufA, NB);
  // x1 pools
  pool_partial_kernel<<<BG * SLICES, 128, 0, stream>>>(bufA, NN, pmax, psum);
  pool_final_kernel<<<BG, 128, 0, stream>>>(pmax, psum, x1v, 1.0f / NN);

  // conv2
  agg_kernel<<<NB, 128, 0, stream>>>(bufA, HH, rs1, csr1, agg, NB);
  mm_kernel<128><<<NB / 8, 128, 0, stream>>>(agg, bufA, HH, w2relT, w2rootT, b2, bufB, NB);

  // topk
  norm_kernel<<<1, 128, 0, stream>>>(pool_w, normv);
  score_kernel<<<NB / 4, 256, 0, stream>>>(bufB, pool_w, normv, score, NB);
  topk_kernel<<<BG, 1024, 0, stream>>>(score, perm);
  h3_kernel<<<(N1 * HH + TB - 1) / TB, TB, 0, stream>>>(bufB, perm, score, bufA);
  newid_kernel<<<(N1 + TB - 1) / TB, TB, 0, stream>>>(perm, new_id);

  // x2 pools (on scaled kept features)
  pool_partial_kernel<<<BG * SLICES, 128, 0, stream>>>(bufA, KK, pmax, psum);
  pool_final_kernel<<<BG, 128, 0, stream>>>(pmax, psum, x2v, 1.0f / KK);

  // CSR2 over remapped kept edges
  deg2_kernel<<<egrid, TB, 0, stream>>>(src, dst, new_id, deg2, EE);
  exscan_kernel<<<1, 1024, 0, stream>>>(deg2, rs2, cursor2, N1);
  scatter2_kernel<<<egrid, TB, 0, stream>>>(src, dst, new_id, cursor2, csr2, EE);

  // conv3
  agg_kernel<<<N1, 128, 0, stream>>>(bufA, HH, rs2, csr2, agg, N1);
  mm_kernel<128><<<N1 / 8, 128, 0, stream>>>(agg, bufA, HH, w3relT, w3rootT, b3, bufB, N1);

  // x3 pools
  pool_partial_kernel<<<BG * SLICES, 128, 0, stream>>>(bufB, KK, pmax, psum);
  pool_final_kernel<<<BG, 128, 0, stream>>>(pmax, psum, x3v, 1.0f / KK);

  // MLP head + log_softmax
  mlp_kernel<<<BG, 128, 0, stream>>>(x1v, x2v, x3v, Wl1, bl1, Wl2, bl2, Wl3, bl3, out);
}

// Round 2
// 522.155 us; speedup vs baseline: 1.2458x; 1.2458x over previous
//
#include <hip/hip_runtime.h>
#include <hip/hip_bf16.h>
#include <math.h>

#define NB 32768      // total nodes (B*N)
#define NN 2048       // nodes per graph
#define BG 16         // graphs
#define KK 1639       // kept per graph
#define N1 (BG*KK)    // 26224 kept nodes total
#define EE 524288     // total edges
#define HH 128        // hidden
#define FIN 64        // input features
#define SLICES 16

// ---------------- CSR build ----------------
__global__ void deg_kernel(const int* __restrict__ dst, int* deg, int n) {
  int e = blockIdx.x * blockDim.x + threadIdx.x;
  if (e < n) atomicAdd(&deg[dst[e]], 1);
}

__global__ void deg2_kernel(const int* __restrict__ src, const int* __restrict__ dst,
                            const int* __restrict__ new_id, int* deg, int n) {
  int e = blockIdx.x * blockDim.x + threadIdx.x;
  if (e < n) {
    int a = new_id[src[e]], d = new_id[dst[e]];
    if (a >= 0 && d >= 0) atomicAdd(&deg[d], 1);
  }
}

// single-block register-blocked exclusive scan (n <= 32768); writes rs[0..n], cursor[0..n-1]
__global__ void exscan_kernel(const int* __restrict__ deg, int* rs, int* cursor, int n) {
  __shared__ int wsum[16];
  int t = threadIdx.x;  // 1024
  int base = t * 32;
  int vals[32];
  int s = 0;
#pragma unroll
  for (int i = 0; i < 32; ++i) {
    int idx = base + i;
    int v = (idx < n) ? deg[idx] : 0;
    vals[i] = s;   // local exclusive prefix
    s += v;
  }
  int lane = t & 63, wid = t >> 6;
  int pre = s;
  for (int off = 1; off < 64; off <<= 1) {
    int u = __shfl_up(pre, off, 64);
    if (lane >= off) pre += u;
  }
  if (lane == 63) wsum[wid] = pre;
  __syncthreads();
  int wbase = 0;
#pragma unroll
  for (int ww = 0; ww < 16; ++ww)
    if (ww < wid) wbase += wsum[ww];
  int texcl = wbase + pre - s;  // exclusive prefix of this thread
#pragma unroll
  for (int i = 0; i < 32; ++i) {
    int idx = base + i;
    if (idx < n) {
      int e = texcl + vals[i];
      rs[idx] = e;
      cursor[idx] = e;
    }
  }
  if (t == 1023) rs[n] = texcl + s;
}

__global__ void scatter_kernel(const int* __restrict__ src, const int* __restrict__ dst,
                               int* cursor, int* csr, int n) {
  int e = blockIdx.x * blockDim.x + threadIdx.x;
  if (e < n) {
    int d = dst[e];
    int p = atomicAdd(&cursor[d], 1);
    csr[p] = src[e];
  }
}

__global__ void scatter2_kernel(const int* __restrict__ src, const int* __restrict__ dst,
                                const int* __restrict__ new_id, int* cursor, int* csr, int n) {
  int e = blockIdx.x * blockDim.x + threadIdx.x;
  if (e < n) {
    int a = new_id[src[e]], d = new_id[dst[e]];
    if (a >= 0 && d >= 0) {
      int p = atomicAdd(&cursor[d], 1);
      csr[p] = a;
    }
  }
}

// ---------------- aggregation (gather-sum, float4, XCD-swizzled) ----------------
// block = 256 threads = 4 waves; each wave handles one node; F4 = feature width / 4
template <int F4>
__global__ void agg_kernel(const float4* __restrict__ feat, const int* __restrict__ rs,
                           const int* __restrict__ csr, float4* __restrict__ agg, int M,
                           int nwg) {
  // bijective XCD-chunk swizzle (m204): XCD x gets a contiguous chunk of node space
  int b = blockIdx.x;
  int q = nwg >> 3, r = nwg & 7, x = b & 7, i = b >> 3;
  int swz = (x < r ? x * (q + 1) : r * (q + 1) + (x - r) * q) + i;
  int node = swz * 4 + (threadIdx.x >> 6);
  if (node >= M) return;
  int lane = threadIdx.x & 63;
  int sub = lane / F4, f4 = lane % F4;  // 64/F4 edges in flight per wave
  int e0 = rs[node], e1 = rs[node + 1];
  float4 acc = make_float4(0.f, 0.f, 0.f, 0.f);
  for (int e = e0 + sub; e < e1; e += 64 / F4) {
    float4 v = feat[(size_t)csr[e] * F4 + f4];
    acc.x += v.x; acc.y += v.y; acc.z += v.z; acc.w += v.w;
  }
  // reduce partial sums across subs (valid in lanes with sub==0)
  acc.x += __shfl_down(acc.x, 32, 64);
  acc.y += __shfl_down(acc.y, 32, 64);
  acc.z += __shfl_down(acc.z, 32, 64);
  acc.w += __shfl_down(acc.w, 32, 64);
  if (F4 == 16) {
    acc.x += __shfl_down(acc.x, 16, 64);
    acc.y += __shfl_down(acc.y, 16, 64);
    acc.z += __shfl_down(acc.z, 16, 64);
    acc.w += __shfl_down(acc.w, 16, 64);
  }
  if (sub == 0) agg[(size_t)node * F4 + f4] = acc;
}

// ---------------- fused conv GEMM: relu([agg|x] @ WcatT + b) ----------------
// KD = per-matrix K (64 or 128); total K = 2*KD. Block 128 threads, 32-row tile.
// Thread layout: 4 row-groups x 32 col-groups; each thread: 8 rows x 4 cols.
template <int KD>
__global__ void mm_kernel(const float4* __restrict__ agg,     // [M][KD/4]
                          const float4* __restrict__ xr,       // [M][ldx4]
                          int ldx4,
                          const float4* __restrict__ wcatT,    // [2*KD][128] as f4: row*32+cg
                          const float* __restrict__ bias, float4* __restrict__ out, int M) {
  const int F4 = KD / 4;
  __shared__ float4 sAX4[32 * 2 * F4];  // 32 rows x (2*KD) floats
  int row0 = blockIdx.x * 32;
  int tid = threadIdx.x;  // 128

  // stage A (agg) and X halves
  for (int idx = tid; idx < 32 * F4; idx += 128) {
    int r = idx / F4, c = idx % F4;
    int row = row0 + r;
    sAX4[r * (2 * F4) + c] =
        (row < M) ? agg[(size_t)row * F4 + c] : make_float4(0.f, 0.f, 0.f, 0.f);
    sAX4[r * (2 * F4) + F4 + c] =
        (row < M) ? xr[(size_t)row * ldx4 + c] : make_float4(0.f, 0.f, 0.f, 0.f);
  }
  __syncthreads();

  int rg = tid >> 5;          // row group 0..3
  int cg = tid & 31;          // col group 0..31 (4 cols each)
  int rbase = rg * 8;

  float4 acc[8];
#pragma unroll
  for (int rr = 0; rr < 8; ++rr) acc[rr] = make_float4(0.f, 0.f, 0.f, 0.f);

  for (int kc = 0; kc < 2 * F4; ++kc) {   // 4 k's per iteration
    float4 w4[4];
#pragma unroll
    for (int kk = 0; kk < 4; ++kk) w4[kk] = wcatT[(size_t)(kc * 4 + kk) * 32 + cg];
    float4 a4[8];
#pragma unroll
    for (int rr = 0; rr < 8; ++rr) a4[rr] = sAX4[(rbase + rr) * (2 * F4) + kc];
#pragma unroll
    for (int kk = 0; kk < 4; ++kk) {
      float4 wv = w4[kk];
#pragma unroll
      for (int rr = 0; rr < 8; ++rr) {
        float av = (kk == 0) ? a4[rr].x : (kk == 1) ? a4[rr].y : (kk == 2) ? a4[rr].z : a4[rr].w;
        acc[rr].x = fmaf(av, wv.x, acc[rr].x);
        acc[rr].y = fmaf(av, wv.y, acc[rr].y);
        acc[rr].z = fmaf(av, wv.z, acc[rr].z);
        acc[rr].w = fmaf(av, wv.w, acc[rr].w);
      }
    }
  }

  float4 b4 = ((const float4*)bias)[cg];
#pragma unroll
  for (int rr = 0; rr < 8; ++rr) {
    int row = row0 + rbase + rr;
    if (row < M) {
      float4 o;
      o.x = fmaxf(acc[rr].x + b4.x, 0.f);
      o.y = fmaxf(acc[rr].y + b4.y, 0.f);
      o.z = fmaxf(acc[rr].z + b4.z, 0.f);
      o.w = fmaxf(acc[rr].w + b4.w, 0.f);
      out[(size_t)row * 32 + cg] = o;
    }
  }
}

// ---------------- weight prep: WcatT[f][o] = f<KD ? Wrel[o][f] : Wroot[o][f-KD] ----------------
__global__ void prep_weights(const float* __restrict__ W1_rel, const float* __restrict__ W1_root,
                             const float* __restrict__ W2_rel, const float* __restrict__ W2_root,
                             const float* __restrict__ W3_rel, const float* __restrict__ W3_root,
                             float* w1catT, float* w2catT, float* w3catT) {
  int idx = blockIdx.x * blockDim.x + threadIdx.x;
  if (idx < 128 * 128) {
    int f = idx >> 7, o = idx & 127;
    w1catT[idx] = (f < 64) ? W1_rel[o * 64 + f] : W1_root[o * 64 + (f - 64)];
  } else if (idx < 128 * 128 + 256 * 128) {
    int j = idx - 128 * 128;
    int f = j >> 7, o = j & 127;
    w2catT[j] = (f < 128) ? W2_rel[o * 128 + f] : W2_root[o * 128 + (f - 128)];
  } else if (idx < 128 * 128 + 2 * 256 * 128) {
    int j = idx - 128 * 128 - 256 * 128;
    int f = j >> 7, o = j & 127;
    w3catT[j] = (f < 128) ? W3_rel[o * 128 + f] : W3_root[o * 128 + (f - 128)];
  }
}

// ---------------- pooling partials ----------------
__global__ void pool_partial_kernel(const float* __restrict__ h, int rows_per_graph,
                                    float* pmax, float* psum) {
  int b = blockIdx.x / SLICES, s = blockIdx.x % SLICES;
  int f = threadIdx.x;
  int per = (rows_per_graph + SLICES - 1) / SLICES;
  int r0 = s * per, r1 = min(rows_per_graph, r0 + per);
  float m = -3.402823466e38f, sum = 0.f;
  for (int r = r0; r < r1; ++r) {
    float v = h[(size_t)(b * rows_per_graph + r) * HH + f];
    m = fmaxf(m, v);
    sum += v;
  }
  pmax[(b * SLICES + s) * HH + f] = m;
  psum[(b * SLICES + s) * HH + f] = sum;
}

// ---------------- scoring / topk ----------------
__global__ void norm_kernel(const float* __restrict__ w, float* normv) {
  __shared__ float sd[128];
  int t = threadIdx.x;
  sd[t] = w[t] * w[t];
  __syncthreads();
  for (int off = 64; off > 0; off >>= 1) {
    if (t < off) sd[t] += sd[t + off];
    __syncthreads();
  }
  if (t == 0) normv[0] = sqrtf(sd[0]);
}

__global__ void score_kernel(const float* __restrict__ h2, const float* __restrict__ w,
                             const float* __restrict__ normv, float* score, int M) {
  int wave = threadIdx.x >> 6;
  int lane = threadIdx.x & 63;
  int i = blockIdx.x * (blockDim.x >> 6) + wave;
  if (i >= M) return;
  float acc = h2[i * HH + lane] * w[lane] + h2[i * HH + 64 + lane] * w[64 + lane];
  for (int off = 32; off > 0; off >>= 1) acc += __shfl_down(acc, off, 64);
  if (lane == 0) score[i] = tanhf(acc / normv[0]);
}

// per-graph bitonic sort of 2048 (score,index) keys; keep top K, tie-break lowest index
__global__ void topk_kernel(const float* __restrict__ score, int* perm) {
  __shared__ unsigned long long k[NN];
  int b = blockIdx.x;
  int tid = threadIdx.x;  // 1024
  for (int i = tid; i < NN; i += 1024) {
    float s = score[b * NN + i];
    unsigned u = __float_as_uint(s);
    u = (u & 0x80000000u) ? ~u : (u | 0x80000000u);
    unsigned long long key = ((unsigned long long)u << 32) | (unsigned)(NN - 1 - i);
    k[i] = ~key;  // ascending sort of ~key == descending by (score, -index)
  }
  __syncthreads();
  for (int kk = 2; kk <= NN; kk <<= 1) {
    for (int j = kk >> 1; j > 0; j >>= 1) {
      for (int t = tid; t < NN; t += 1024) {
        int ixj = t ^ j;
        if (ixj > t) {
          bool up = ((t & kk) == 0);
          unsigned long long a = k[t], c = k[ixj];
          if ((a > c) == up) { k[t] = c; k[ixj] = a; }
        }
      }
      __syncthreads();
    }
  }
  for (int j = tid; j < KK; j += 1024) {
    unsigned long long key = ~k[j];
    int i = (NN - 1) - (int)(key & 0xffffffffu);
    perm[b * KK + j] = b * NN + i;
  }
}

// gather kept rows, scale by score, and write new_id (fused)
__global__ void h3_kernel(const float4* __restrict__ h2, const int* __restrict__ perm,
                          const float* __restrict__ score, float4* __restrict__ h3,
                          int* new_id) {
  int idx = blockIdx.x * blockDim.x + threadIdx.x;  // over N1*32 float4s
  if (idx < N1 * 32) {
    int g = idx >> 5, c = idx & 31;
    int p = perm[g];
    if (c == 0) new_id[p] = g;
    float s = score[p];
    float4 v = h2[(size_t)p * 32 + c];
    v.x *= s; v.y *= s; v.z *= s; v.w *= s;
    h3[idx] = v;
  }
}

// ---------------- final: pool-final x3 + MLP + log_softmax ----------------
__global__ void mlp_kernel(const float* __restrict__ pm1, const float* __restrict__ ps1,
                           const float* __restrict__ pm2, const float* __restrict__ ps2,
                           const float* __restrict__ pm3, const float* __restrict__ ps3,
                           const float* __restrict__ Wl1, const float* __restrict__ bl1,
                           const float* __restrict__ Wl2, const float* __restrict__ bl2,
                           const float* __restrict__ Wl3, const float* __restrict__ bl3,
                           float* out) {
  __shared__ float z[256], a1[128], a2[64], a3[10], red[2];
  int b = blockIdx.x, t = threadIdx.x;  // 128 threads
  float m1 = -3.402823466e38f, m2 = m1, m3 = m1;
  float s1 = 0.f, s2 = 0.f, s3 = 0.f;
  for (int s = 0; s < SLICES; ++s) {
    int o = (b * SLICES + s) * 128 + t;
    m1 = fmaxf(m1, pm1[o]); s1 += ps1[o];
    m2 = fmaxf(m2, pm2[o]); s2 += ps2[o];
    m3 = fmaxf(m3, pm3[o]); s3 += ps3[o];
  }
  z[t] = m1 + m2 + m3;
  z[128 + t] = s1 * (1.f / NN) + (s2 + s3) * (1.f / KK);
  __syncthreads();
  {
    float acc = bl1[t];
    for (int q = 0; q < 256; ++q) acc = fmaf(Wl1[t * 256 + q], z[q], acc);
    a1[t] = fmaxf(acc, 0.f);
  }
  __syncthreads();
  if (t < 64) {
    float acc = bl2[t];
    for (int q = 0; q < 128; ++q) acc = fmaf(Wl2[t * 128 + q], a1[q], acc);
    a2[t] = fmaxf(acc, 0.f);
  }
  __syncthreads();
  if (t < 10) {
    float acc = bl3[t];
    for (int q = 0; q < 64; ++q) acc = fmaf(Wl3[t * 64 + q], a2[q], acc);
    a3[t] = acc;
  }
  __syncthreads();
  if (t == 0) {
    float m = a3[0];
    for (int i = 1; i < 10; ++i) m = fmaxf(m, a3[i]);
    float s = 0.f;
    for (int i = 0; i < 10; ++i) s += expf(a3[i] - m);
    red[0] = m;
    red[1] = logf(s);
  }
  __syncthreads();
  if (t < 10) out[b * 10 + t] = a3[t] - red[0] - red[1];
}

extern "C" void kernel_launch(void* const* d_in, const int* in_sizes, int n_in,
                              void* d_out, int out_size, void* d_ws, size_t ws_size,
                              hipStream_t stream) {
  const float* x       = (const float*)d_in[0];
  const int*   src     = (const int*)d_in[1];
  const int*   dst     = (const int*)d_in[2];
  const float* W1_rel  = (const float*)d_in[3];
  const float* b1      = (const float*)d_in[4];
  const float* W1_root = (const float*)d_in[5];
  const float* W2_rel  = (const float*)d_in[6];
  const float* b2      = (const float*)d_in[7];
  const float* W2_root = (const float*)d_in[8];
  const float* W3_rel  = (const float*)d_in[9];
  const float* b3      = (const float*)d_in[10];
  const float* W3_root = (const float*)d_in[11];
  const float* pool_w  = (const float*)d_in[12];
  const float* Wl1     = (const float*)d_in[13];
  const float* bl1     = (const float*)d_in[14];
  const float* Wl2     = (const float*)d_in[15];
  const float* bl2     = (const float*)d_in[16];
  const float* Wl3     = (const float*)d_in[17];
  const float* bl3     = (const float*)d_in[18];
  float* out = (float*)d_out;

  // workspace layout
  char* w = (char*)d_ws;
  size_t off = 0;
  auto alloc = [&](size_t bytes) -> char* {
    off = (off + 255) & ~(size_t)255;
    char* p = w + off;
    off += bytes;
    return p;
  };
  int* degs     = (int*)alloc((NB + N1) * 4);  // deg1 | deg2 contiguous (one memset)
  int* deg1     = degs;
  int* deg2     = degs + NB;
  int* rs1      = (int*)alloc((NB + 1) * 4);
  int* cursor1  = (int*)alloc(NB * 4);
  int* csr1     = (int*)alloc((size_t)EE * 4);
  int* rs2      = (int*)alloc((N1 + 1) * 4);
  int* cursor2  = (int*)alloc(N1 * 4);
  int* csr2     = (int*)alloc((size_t)EE * 4);
  int* new_id   = (int*)alloc(NB * 4);
  int* perm     = (int*)alloc(N1 * 4);
  float* w1catT = (float*)alloc(128 * 128 * 4);
  float* w2catT = (float*)alloc(256 * 128 * 4);
  float* w3catT = (float*)alloc(256 * 128 * 4);
  float* aggbuf = (float*)alloc((size_t)NB * HH * 4);
  float* bufA   = (float*)alloc((size_t)NB * HH * 4);  // h1, then h3
  float* bufB   = (float*)alloc((size_t)NB * HH * 4);  // h2, then h4
  float* score  = (float*)alloc(NB * 4);
  float* normv  = (float*)alloc(64);
  float* pm1    = (float*)alloc(BG * SLICES * HH * 4);
  float* ps1    = (float*)alloc(BG * SLICES * HH * 4);
  float* pm2    = (float*)alloc(BG * SLICES * HH * 4);
  float* ps2    = (float*)alloc(BG * SLICES * HH * 4);
  float* pm3    = (float*)alloc(BG * SLICES * HH * 4);
  float* ps3    = (float*)alloc(BG * SLICES * HH * 4);
  if (off > ws_size) return;  // workspace too small: fail visibly

  const int TB = 256;
  const int egrid = (EE + TB - 1) / TB;

  hipMemsetAsync(degs, 0, (NB + N1) * 4, stream);
  hipMemsetAsync(new_id, 0xFF, NB * 4, stream);  // -1

  prep_weights<<<(128 * 128 + 2 * 256 * 128 + TB - 1) / TB, TB, 0, stream>>>(
      W1_rel, W1_root, W2_rel, W2_root, W3_rel, W3_root, w1catT, w2catT, w3catT);

  // CSR1 (src -> dst)
  deg_kernel<<<egrid, TB, 0, stream>>>(dst, deg1, EE);
  exscan_kernel<<<1, 1024, 0, stream>>>(deg1, rs1, cursor1, NB);
  scatter_kernel<<<egrid, TB, 0, stream>>>(src, dst, cursor1, csr1, EE);

  // conv1 (K = 64 agg + 64 root)
  agg_kernel<16><<<NB / 4, 256, 0, stream>>>((const float4*)x, rs1, csr1, (float4*)aggbuf,
                                             NB, NB / 4);
  mm_kernel<64><<<NB / 32, 128, 0, stream>>>((const float4*)aggbuf, (const float4*)x, 16,
                                             (const float4*)w1catT, b1, (float4*)bufA, NB);
  pool_partial_kernel<<<BG * SLICES, 128, 0, stream>>>(bufA, NN, pm1, ps1);

  // conv2
  agg_kernel<32><<<NB / 4, 256, 0, stream>>>((const float4*)bufA, rs1, csr1, (float4*)aggbuf,
                                             NB, NB / 4);
  mm_kernel<128><<<NB / 32, 128, 0, stream>>>((const float4*)aggbuf, (const float4*)bufA, 32,
                                              (const float4*)w2catT, b2, (float4*)bufB, NB);

  // topk
  norm_kernel<<<1, 128, 0, stream>>>(pool_w, normv);
  score_kernel<<<NB / 4, 256, 0, stream>>>(bufB, pool_w, normv, score, NB);
  topk_kernel<<<BG, 1024, 0, stream>>>(score, perm);
  h3_kernel<<<(N1 * 32 + TB - 1) / TB, TB, 0, stream>>>((const float4*)bufB, perm, score,
                                                        (float4*)bufA, new_id);
  pool_partial_kernel<<<BG * SLICES, 128, 0, stream>>>(bufA, KK, pm2, ps2);

  // CSR2 over remapped kept edges
  deg2_kernel<<<egrid, TB, 0, stream>>>(src, dst, new_id, deg2, EE);
  exscan_kernel<<<1, 1024, 0, stream>>>(deg2, rs2, cursor2, N1);
  scatter2_kernel<<<egrid, TB, 0, stream>>>(src, dst, new_id, cursor2, csr2, EE);

  // conv3
  agg_kernel<32><<<(N1 + 3) / 4, 256, 0, stream>>>((const float4*)bufA, rs2, csr2,
                                                   (float4*)aggbuf, N1, (N1 + 3) / 4);
  mm_kernel<128><<<(N1 + 31) / 32, 128, 0, stream>>>((const float4*)aggbuf, (const float4*)bufA,
                                                     32, (const float4*)w3catT, b3,
                                                     (float4*)bufB, N1);
  pool_partial_kernel<<<BG * SLICES, 128, 0, stream>>>(bufB, KK, pm3, ps3);

  // pool finals + MLP head + log_softmax (fused)
  mlp_kernel<<<BG, 128, 0, stream>>>(pm1, ps1, pm2, ps2, pm3, ps3,
                                     Wl1, bl1, Wl2, bl2, Wl3, bl3, out);
}

// Round 3
// 504.156 us; speedup vs baseline: 1.2903x; 1.0357x over previous
//
#include <hip/hip_runtime.h>
#include <hip/hip_bf16.h>
#include <math.h>

#define NB 32768      // total nodes (B*N)
#define NN 2048       // nodes per graph
#define BG 16         // graphs
#define KK 1639       // kept per graph
#define N1 (BG*KK)    // 26224 kept nodes total
#define EE 524288     // total edges
#define HH 128        // hidden
#define FIN 64        // input features
#define SLICES 16

using half8 = __attribute__((ext_vector_type(8))) _Float16;
using f32x4 = __attribute__((ext_vector_type(4))) float;

// ---------------- CSR build ----------------
__global__ void deg_kernel(const int* __restrict__ dst, int* deg, int n) {
  int e = blockIdx.x * blockDim.x + threadIdx.x;
  if (e < n) atomicAdd(&deg[dst[e]], 1);
}

__global__ void deg2_kernel(const int* __restrict__ src, const int* __restrict__ dst,
                            const int* __restrict__ new_id, int* deg, int n) {
  int e = blockIdx.x * blockDim.x + threadIdx.x;
  if (e < n) {
    int a = new_id[src[e]], d = new_id[dst[e]];
    if (a >= 0 && d >= 0) atomicAdd(&deg[d], 1);
  }
}

// single-block register-blocked exclusive scan (n <= 32768); writes rs[0..n], cursor[0..n-1]
__global__ void exscan_kernel(const int* __restrict__ deg, int* rs, int* cursor, int n) {
  __shared__ int wsum[16];
  int t = threadIdx.x;  // 1024
  int base = t * 32;
  int vals[32];
  int s = 0;
#pragma unroll
  for (int i = 0; i < 32; ++i) {
    int idx = base + i;
    int v = (idx < n) ? deg[idx] : 0;
    vals[i] = s;   // local exclusive prefix
    s += v;
  }
  int lane = t & 63, wid = t >> 6;
  int pre = s;
  for (int off = 1; off < 64; off <<= 1) {
    int u = __shfl_up(pre, off, 64);
    if (lane >= off) pre += u;
  }
  if (lane == 63) wsum[wid] = pre;
  __syncthreads();
  int wbase = 0;
#pragma unroll
  for (int ww = 0; ww < 16; ++ww)
    if (ww < wid) wbase += wsum[ww];
  int texcl = wbase + pre - s;  // exclusive prefix of this thread
#pragma unroll
  for (int i = 0; i < 32; ++i) {
    int idx = base + i;
    if (idx < n) {
      int e = texcl + vals[i];
      rs[idx] = e;
      cursor[idx] = e;
    }
  }
  if (t == 1023) rs[n] = texcl + s;
}

__global__ void scatter_kernel(const int* __restrict__ src, const int* __restrict__ dst,
                               int* cursor, int* csr, int n) {
  int e = blockIdx.x * blockDim.x + threadIdx.x;
  if (e < n) {
    int d = dst[e];
    int p = atomicAdd(&cursor[d], 1);
    csr[p] = src[e];
  }
}

__global__ void scatter2_kernel(const int* __restrict__ src, const int* __restrict__ dst,
                                const int* __restrict__ new_id, int* cursor, int* csr, int n) {
  int e = blockIdx.x * blockDim.x + threadIdx.x;
  if (e < n) {
    int a = new_id[src[e]], d = new_id[dst[e]];
    if (a >= 0 && d >= 0) {
      int p = atomicAdd(&cursor[d], 1);
      csr[p] = a;
    }
  }
}

// ---------------- aggregation (gather-sum, float4, XCD-swizzled) ----------------
// block = 256 threads = 4 waves; each wave handles one node; F4 = feature width / 4
template <int F4>
__global__ void agg_kernel(const float4* __restrict__ feat, const int* __restrict__ rs,
                           const int* __restrict__ csr, float4* __restrict__ agg, int M,
                           int nwg) {
  // bijective XCD-chunk swizzle (m204): XCD x gets a contiguous chunk of node space
  int b = blockIdx.x;
  int q = nwg >> 3, r = nwg & 7, x = b & 7, i = b >> 3;
  int swz = (x < r ? x * (q + 1) : r * (q + 1) + (x - r) * q) + i;
  int node = swz * 4 + (threadIdx.x >> 6);
  if (node >= M) return;
  int lane = threadIdx.x & 63;
  int sub = lane / F4, f4 = lane % F4;  // 64/F4 edges in flight per wave
  int e0 = rs[node], e1 = rs[node + 1];
  float4 acc = make_float4(0.f, 0.f, 0.f, 0.f);
  for (int e = e0 + sub; e < e1; e += 64 / F4) {
    float4 v = feat[(size_t)csr[e] * F4 + f4];
    acc.x += v.x; acc.y += v.y; acc.z += v.z; acc.w += v.w;
  }
  // reduce partial sums across subs (valid in lanes with sub==0)
  acc.x += __shfl_down(acc.x, 32, 64);
  acc.y += __shfl_down(acc.y, 32, 64);
  acc.z += __shfl_down(acc.z, 32, 64);
  acc.w += __shfl_down(acc.w, 32, 64);
  if (F4 == 16) {
    acc.x += __shfl_down(acc.x, 16, 64);
    acc.y += __shfl_down(acc.y, 16, 64);
    acc.z += __shfl_down(acc.z, 16, 64);
    acc.w += __shfl_down(acc.w, 16, 64);
  }
  if (sub == 0) agg[(size_t)node * F4 + f4] = acc;
}

// ---------------- fused conv GEMM via f16 split-precision MFMA ----------------
// out = relu([agg|x] @ Wcat^T + b); Wcat pre-split into Wh + Wl (f16), [128][KTOT].
// Error ~2^-22 (3-product hi/lo scheme) — f32-class accuracy.
// Block: 256 threads = 4 waves; each wave computes 16 rows x 128 cols.
// MFMA 16x16x32_f16 fragments: A row = lane&15, k = (lane>>4)*8+j (8 contiguous f32
// from global, converted in-reg); B col = lane&15, k likewise (16B f16 loads from Wh/Wl);
// C/D: row = (lane>>4)*4+reg, col = lane&15 (m89-verified mapping).
template <int KD1, int KD2>
__global__ void conv_mfma(const float* __restrict__ agg, const float* __restrict__ xr,
                          const _Float16* __restrict__ Wh, const _Float16* __restrict__ Wl,
                          const float* __restrict__ bias, float* __restrict__ out, int M) {
  constexpr int KTOT = KD1 + KD2;
  int wid = threadIdx.x >> 6, lane = threadIdx.x & 63;
  int row0 = blockIdx.x * 64 + wid * 16;
  int arow = row0 + (lane & 15);
  if (arow >= M) arow = M - 1;  // clamp: stores are guarded, padded rows never written
  int kgrp = (lane >> 4) * 8;
  int col = lane & 15;

  f32x4 acc[8];
#pragma unroll
  for (int c = 0; c < 8; ++c) acc[c] = (f32x4){0.f, 0.f, 0.f, 0.f};

#pragma unroll 2
  for (int k0 = 0; k0 < KTOT; k0 += 32) {
    int kk = k0 + kgrp;  // wave-uniform branch: KD1 % 32 == 0
    const float* srcp = (kk < KD1) ? (agg + (size_t)arow * KD1 + kk)
                                   : (xr + (size_t)arow * KD2 + (kk - KD1));
    float4 a0 = *(const float4*)srcp;
    float4 a1 = *(const float4*)(srcp + 4);
    float av[8] = {a0.x, a0.y, a0.z, a0.w, a1.x, a1.y, a1.z, a1.w};
    half8 ah, al;
#pragma unroll
    for (int j = 0; j < 8; ++j) {
      _Float16 h = (_Float16)av[j];
      ah[j] = h;
      al[j] = (_Float16)(av[j] - (float)h);
    }
#pragma unroll
    for (int c = 0; c < 8; ++c) {
      size_t wof = (size_t)(c * 16 + col) * KTOT + kk;
      half8 bh = *(const half8*)(Wh + wof);
      half8 bl = *(const half8*)(Wl + wof);
      acc[c] = __builtin_amdgcn_mfma_f32_16x16x32_f16(al, bh, acc[c], 0, 0, 0);
      acc[c] = __builtin_amdgcn_mfma_f32_16x16x32_f16(ah, bl, acc[c], 0, 0, 0);
      acc[c] = __builtin_amdgcn_mfma_f32_16x16x32_f16(ah, bh, acc[c], 0, 0, 0);
    }
  }

  int orow0 = row0 + (lane >> 4) * 4;
#pragma unroll
  for (int c = 0; c < 8; ++c) {
    int ocol = c * 16 + col;
    float bv = bias[ocol];
#pragma unroll
    for (int r = 0; r < 4; ++r) {
      int orow = orow0 + r;
      if (orow < M) out[(size_t)orow * HH + ocol] = fmaxf(acc[c][r] + bv, 0.f);
    }
  }
}

// ---------------- weight prep: split Wcat[o][k] into f16 hi + lo planes ----------------
__global__ void prep_weights_f16(const float* __restrict__ W1_rel, const float* __restrict__ W1_root,
                                 const float* __restrict__ W2_rel, const float* __restrict__ W2_root,
                                 const float* __restrict__ W3_rel, const float* __restrict__ W3_root,
                                 _Float16* wh1, _Float16* wl1, _Float16* wh2, _Float16* wl2,
                                 _Float16* wh3, _Float16* wl3) {
  int idx = blockIdx.x * blockDim.x + threadIdx.x;
  float v;
  _Float16* ph;
  _Float16* pl;
  int j;
  if (idx < 128 * 128) {
    j = idx;
    int o = j >> 7, k = j & 127;
    v = (k < 64) ? W1_rel[o * 64 + k] : W1_root[o * 64 + (k - 64)];
    ph = wh1; pl = wl1;
  } else if (idx < 128 * 128 + 128 * 256) {
    j = idx - 128 * 128;
    int o = j >> 8, k = j & 255;
    v = (k < 128) ? W2_rel[o * 128 + k] : W2_root[o * 128 + (k - 128)];
    ph = wh2; pl = wl2;
  } else if (idx < 128 * 128 + 2 * 128 * 256) {
    j = idx - 128 * 128 - 128 * 256;
    int o = j >> 8, k = j & 255;
    v = (k < 128) ? W3_rel[o * 128 + k] : W3_root[o * 128 + (k - 128)];
    ph = wh3; pl = wl3;
  } else {
    return;
  }
  _Float16 h = (_Float16)v;
  ph[j] = h;
  pl[j] = (_Float16)(v - (float)h);
}

// ---------------- pooling partials ----------------
__global__ void pool_partial_kernel(const float* __restrict__ h, int rows_per_graph,
                                    float* pmax, float* psum) {
  int b = blockIdx.x / SLICES, s = blockIdx.x % SLICES;
  int f = threadIdx.x;
  int per = (rows_per_graph + SLICES - 1) / SLICES;
  int r0 = s * per, r1 = min(rows_per_graph, r0 + per);
  float m = -3.402823466e38f, sum = 0.f;
  for (int r = r0; r < r1; ++r) {
    float v = h[(size_t)(b * rows_per_graph + r) * HH + f];
    m = fmaxf(m, v);
    sum += v;
  }
  pmax[(b * SLICES + s) * HH + f] = m;
  psum[(b * SLICES + s) * HH + f] = sum;
}

// ---------------- scoring / topk ----------------
__global__ void norm_kernel(const float* __restrict__ w, float* normv) {
  __shared__ float sd[128];
  int t = threadIdx.x;
  sd[t] = w[t] * w[t];
  __syncthreads();
  for (int off = 64; off > 0; off >>= 1) {
    if (t < off) sd[t] += sd[t + off];
    __syncthreads();
  }
  if (t == 0) normv[0] = sqrtf(sd[0]);
}

__global__ void score_kernel(const float* __restrict__ h2, const float* __restrict__ w,
                             const float* __restrict__ normv, float* score, int M) {
  int wave = threadIdx.x >> 6;
  int lane = threadIdx.x & 63;
  int i = blockIdx.x * (blockDim.x >> 6) + wave;
  if (i >= M) return;
  float acc = h2[i * HH + lane] * w[lane] + h2[i * HH + 64 + lane] * w[64 + lane];
  for (int off = 32; off > 0; off >>= 1) acc += __shfl_down(acc, off, 64);
  if (lane == 0) score[i] = tanhf(acc / normv[0]);
}

// per-graph bitonic sort of 2048 (score,index) keys; keep top K, tie-break lowest index
__global__ void topk_kernel(const float* __restrict__ score, int* perm) {
  __shared__ unsigned long long k[NN];
  int b = blockIdx.x;
  int tid = threadIdx.x;  // 1024
  for (int i = tid; i < NN; i += 1024) {
    float s = score[b * NN + i];
    unsigned u = __float_as_uint(s);
    u = (u & 0x80000000u) ? ~u : (u | 0x80000000u);
    unsigned long long key = ((unsigned long long)u << 32) | (unsigned)(NN - 1 - i);
    k[i] = ~key;  // ascending sort of ~key == descending by (score, -index)
  }
  __syncthreads();
  for (int kk = 2; kk <= NN; kk <<= 1) {
    for (int j = kk >> 1; j > 0; j >>= 1) {
      for (int t = tid; t < NN; t += 1024) {
        int ixj = t ^ j;
        if (ixj > t) {
          bool up = ((t & kk) == 0);
          unsigned long long a = k[t], c = k[ixj];
          if ((a > c) == up) { k[t] = c; k[ixj] = a; }
        }
      }
      __syncthreads();
    }
  }
  for (int j = tid; j < KK; j += 1024) {
    unsigned long long key = ~k[j];
    int i = (NN - 1) - (int)(key & 0xffffffffu);
    perm[b * KK + j] = b * NN + i;
  }
}

// gather kept rows, scale by score, and write new_id (fused)
__global__ void h3_kernel(const float4* __restrict__ h2, const int* __restrict__ perm,
                          const float* __restrict__ score, float4* __restrict__ h3,
                          int* new_id) {
  int idx = blockIdx.x * blockDim.x + threadIdx.x;  // over N1*32 float4s
  if (idx < N1 * 32) {
    int g = idx >> 5, c = idx & 31;
    int p = perm[g];
    if (c == 0) new_id[p] = g;
    float s = score[p];
    float4 v = h2[(size_t)p * 32 + c];
    v.x *= s; v.y *= s; v.z *= s; v.w *= s;
    h3[idx] = v;
  }
}

// ---------------- final: pool-final x3 + MLP + log_softmax ----------------
__global__ void mlp_kernel(const float* __restrict__ pm1, const float* __restrict__ ps1,
                           const float* __restrict__ pm2, const float* __restrict__ ps2,
                           const float* __restrict__ pm3, const float* __restrict__ ps3,
                           const float* __restrict__ Wl1, const float* __restrict__ bl1,
                           const float* __restrict__ Wl2, const float* __restrict__ bl2,
                           const float* __restrict__ Wl3, const float* __restrict__ bl3,
                           float* out) {
  __shared__ float z[256], a1[128], a2[64], a3[10], red[2];
  int b = blockIdx.x, t = threadIdx.x;  // 128 threads
  float m1 = -3.402823466e38f, m2 = m1, m3 = m1;
  float s1 = 0.f, s2 = 0.f, s3 = 0.f;
  for (int s = 0; s < SLICES; ++s) {
    int o = (b * SLICES + s) * 128 + t;
    m1 = fmaxf(m1, pm1[o]); s1 += ps1[o];
    m2 = fmaxf(m2, pm2[o]); s2 += ps2[o];
    m3 = fmaxf(m3, pm3[o]); s3 += ps3[o];
  }
  z[t] = m1 + m2 + m3;
  z[128 + t] = s1 * (1.f / NN) + (s2 + s3) * (1.f / KK);
  __syncthreads();
  {
    float acc = bl1[t];
    for (int q = 0; q < 256; ++q) acc = fmaf(Wl1[t * 256 + q], z[q], acc);
    a1[t] = fmaxf(acc, 0.f);
  }
  __syncthreads();
  if (t < 64) {
    float acc = bl2[t];
    for (int q = 0; q < 128; ++q) acc = fmaf(Wl2[t * 128 + q], a1[q], acc);
    a2[t] = fmaxf(acc, 0.f);
  }
  __syncthreads();
  if (t < 10) {
    float acc = bl3[t];
    for (int q = 0; q < 64; ++q) acc = fmaf(Wl3[t * 64 + q], a2[q], acc);
    a3[t] = acc;
  }
  __syncthreads();
  if (t == 0) {
    float m = a3[0];
    for (int i = 1; i < 10; ++i) m = fmaxf(m, a3[i]);
    float s = 0.f;
    for (int i = 0; i < 10; ++i) s += expf(a3[i] - m);
    red[0] = m;
    red[1] = logf(s);
  }
  __syncthreads();
  if (t < 10) out[b * 10 + t] = a3[t] - red[0] - red[1];
}

extern "C" void kernel_launch(void* const* d_in, const int* in_sizes, int n_in,
                              void* d_out, int out_size, void* d_ws, size_t ws_size,
                              hipStream_t stream) {
  const float* x       = (const float*)d_in[0];
  const int*   src     = (const int*)d_in[1];
  const int*   dst     = (const int*)d_in[2];
  const float* W1_rel  = (const float*)d_in[3];
  const float* b1      = (const float*)d_in[4];
  const float* W1_root = (const float*)d_in[5];
  const float* W2_rel  = (const float*)d_in[6];
  const float* b2      = (const float*)d_in[7];
  const float* W2_root = (const float*)d_in[8];
  const float* W3_rel  = (const float*)d_in[9];
  const float* b3      = (const float*)d_in[10];
  const float* W3_root = (const float*)d_in[11];
  const float* pool_w  = (const float*)d_in[12];
  const float* Wl1     = (const float*)d_in[13];
  const float* bl1     = (const float*)d_in[14];
  const float* Wl2     = (const float*)d_in[15];
  const float* bl2     = (const float*)d_in[16];
  const float* Wl3     = (const float*)d_in[17];
  const float* bl3     = (const float*)d_in[18];
  float* out = (float*)d_out;

  // workspace layout
  char* w = (char*)d_ws;
  size_t off = 0;
  auto alloc = [&](size_t bytes) -> char* {
    off = (off + 255) & ~(size_t)255;
    char* p = w + off;
    off += bytes;
    return p;
  };
  int* degs     = (int*)alloc((NB + N1) * 4);  // deg1 | deg2 contiguous (one memset)
  int* deg1     = degs;
  int* deg2     = degs + NB;
  int* rs1      = (int*)alloc((NB + 1) * 4);
  int* cursor1  = (int*)alloc(NB * 4);
  int* csr1     = (int*)alloc((size_t)EE * 4);
  int* rs2      = (int*)alloc((N1 + 1) * 4);
  int* cursor2  = (int*)alloc(N1 * 4);
  int* csr2     = (int*)alloc((size_t)EE * 4);
  int* new_id   = (int*)alloc(NB * 4);
  int* perm     = (int*)alloc(N1 * 4);
  _Float16* wh1 = (_Float16*)alloc(128 * 128 * 2);
  _Float16* wl1 = (_Float16*)alloc(128 * 128 * 2);
  _Float16* wh2 = (_Float16*)alloc(128 * 256 * 2);
  _Float16* wl2 = (_Float16*)alloc(128 * 256 * 2);
  _Float16* wh3 = (_Float16*)alloc(128 * 256 * 2);
  _Float16* wl3 = (_Float16*)alloc(128 * 256 * 2);
  float* aggbuf = (float*)alloc((size_t)NB * HH * 4);
  float* bufA   = (float*)alloc((size_t)NB * HH * 4);  // h1, then h3
  float* bufB   = (float*)alloc((size_t)NB * HH * 4);  // h2, then h4
  float* score  = (float*)alloc(NB * 4);
  float* normv  = (float*)alloc(64);
  float* pm1    = (float*)alloc(BG * SLICES * HH * 4);
  float* ps1    = (float*)alloc(BG * SLICES * HH * 4);
  float* pm2    = (float*)alloc(BG * SLICES * HH * 4);
  float* ps2    = (float*)alloc(BG * SLICES * HH * 4);
  float* pm3    = (float*)alloc(BG * SLICES * HH * 4);
  float* ps3    = (float*)alloc(BG * SLICES * HH * 4);
  if (off > ws_size) return;  // workspace too small: fail visibly

  const int TB = 256;
  const int egrid = (EE + TB - 1) / TB;

  hipMemsetAsync(degs, 0, (NB + N1) * 4, stream);
  hipMemsetAsync(new_id, 0xFF, NB * 4, stream);  // -1

  prep_weights_f16<<<(128 * 128 + 2 * 128 * 256 + TB - 1) / TB, TB, 0, stream>>>(
      W1_rel, W1_root, W2_rel, W2_root, W3_rel, W3_root, wh1, wl1, wh2, wl2, wh3, wl3);

  // CSR1 (src -> dst)
  deg_kernel<<<egrid, TB, 0, stream>>>(dst, deg1, EE);
  exscan_kernel<<<1, 1024, 0, stream>>>(deg1, rs1, cursor1, NB);
  scatter_kernel<<<egrid, TB, 0, stream>>>(src, dst, cursor1, csr1, EE);

  // conv1 (K = 64 agg + 64 root)
  agg_kernel<16><<<NB / 4, 256, 0, stream>>>((const float4*)x, rs1, csr1, (float4*)aggbuf,
                                             NB, NB / 4);
  conv_mfma<64, 64><<<NB / 64, 256, 0, stream>>>(aggbuf, x, wh1, wl1, b1, bufA, NB);
  pool_partial_kernel<<<BG * SLICES, 128, 0, stream>>>(bufA, NN, pm1, ps1);

  // conv2
  agg_kernel<32><<<NB / 4, 256, 0, stream>>>((const float4*)bufA, rs1, csr1, (float4*)aggbuf,
                                             NB, NB / 4);
  conv_mfma<128, 128><<<NB / 64, 256, 0, stream>>>(aggbuf, bufA, wh2, wl2, b2, bufB, NB);

  // topk
  norm_kernel<<<1, 128, 0, stream>>>(pool_w, normv);
  score_kernel<<<NB / 4, 256, 0, stream>>>(bufB, pool_w, normv, score, NB);
  topk_kernel<<<BG, 1024, 0, stream>>>(score, perm);
  h3_kernel<<<(N1 * 32 + TB - 1) / TB, TB, 0, stream>>>((const float4*)bufB, perm, score,
                                                        (float4*)bufA, new_id);
  pool_partial_kernel<<<BG * SLICES, 128, 0, stream>>>(bufA, KK, pm2, ps2);

  // CSR2 over remapped kept edges
  deg2_kernel<<<egrid, TB, 0, stream>>>(src, dst, new_id, deg2, EE);
  exscan_kernel<<<1, 1024, 0, stream>>>(deg2, rs2, cursor2, N1);
  scatter2_kernel<<<egrid, TB, 0, stream>>>(src, dst, new_id, cursor2, csr2, EE);

  // conv3
  agg_kernel<32><<<(N1 + 3) / 4, 256, 0, stream>>>((const float4*)bufA, rs2, csr2,
                                                   (float4*)aggbuf, N1, (N1 + 3) / 4);
  conv_mfma<128, 128><<<(N1 + 63) / 64, 256, 0, stream>>>(aggbuf, bufA, wh3, wl3, b3, bufB, N1);
  pool_partial_kernel<<<BG * SLICES, 128, 0, stream>>>(bufB, KK, pm3, ps3);

  // pool finals + MLP head + log_softmax (fused)
  mlp_kernel<<<BG, 128, 0, stream>>>(pm1, ps1, pm2, ps2, pm3, ps3,
                                     Wl1, bl1, Wl2, bl2, Wl3, bl3, out);
}

// Round 4
// 436.177 us; speedup vs baseline: 1.4914x; 1.1559x over previous
//
#include <hip/hip_runtime.h>
#include <hip/hip_bf16.h>
#include <math.h>

#define NB 32768      // total nodes (B*N)
#define NN 2048       // nodes per graph
#define BG 16         // graphs
#define KK 1639       // kept per graph
#define N1 (BG*KK)    // 26224 kept nodes total
#define EE 524288     // total edges
#define HH 128        // hidden
#define FIN 64        // input features
#define SLICES 16

using half8 = __attribute__((ext_vector_type(8))) _Float16;
using f32x4 = __attribute__((ext_vector_type(4))) float;

// ---------------- CSR build ----------------
__global__ void deg_kernel(const int* __restrict__ dst, int* deg, int n) {
  int e = blockIdx.x * blockDim.x + threadIdx.x;
  if (e < n) atomicAdd(&deg[dst[e]], 1);
}

__global__ void deg2_kernel(const int* __restrict__ src, const int* __restrict__ dst,
                            const int* __restrict__ new_id, int* deg, int n) {
  int e = blockIdx.x * blockDim.x + threadIdx.x;
  if (e < n) {
    int a = new_id[src[e]], d = new_id[dst[e]];
    if (a >= 0 && d >= 0) atomicAdd(&deg[d], 1);
  }
}

// single-block coalesced exclusive scan over tiles of 4096 (int4/lane);
// writes rs[0..n] and cursor[0..n-1]. Caller must pad deg so int4 reads up to
// ceil(n/4096)*4096 stay in-bounds.
__global__ void exscan_kernel(const int* __restrict__ deg, int* rs, int* cursor, int n) {
  __shared__ int wsum[16];
  __shared__ int carry;
  int t = threadIdx.x;  // 1024
  int lane = t & 63, wid = t >> 6;
  if (t == 0) carry = 0;
  __syncthreads();
  int ntiles = (n + 4095) >> 12;
  for (int tile = 0; tile < ntiles; ++tile) {
    int idx = (tile << 12) + t * 4;
    int4 v4 = *(const int4*)(deg + idx);  // coalesced 16B/lane (padded alloc)
    int v0 = (idx + 0 < n) ? v4.x : 0;
    int v1 = (idx + 1 < n) ? v4.y : 0;
    int v2 = (idx + 2 < n) ? v4.z : 0;
    int v3 = (idx + 3 < n) ? v4.w : 0;
    int s = v0 + v1 + v2 + v3;
    int pre = s;
#pragma unroll
    for (int off = 1; off < 64; off <<= 1) {
      int u = __shfl_up(pre, off, 64);
      if (lane >= off) pre += u;
    }
    if (lane == 63) wsum[wid] = pre;
    __syncthreads();
    int wbase = 0;
#pragma unroll
    for (int ww = 0; ww < 16; ++ww)
      if (ww < wid) wbase += wsum[ww];
    int ex = carry + wbase + (pre - s);
    int4 e4 = make_int4(ex, ex + v0, ex + v0 + v1, ex + v0 + v1 + v2);
    if (idx + 3 < n) {
      *(int4*)(rs + idx) = e4;
      *(int4*)(cursor + idx) = e4;
    } else {
      if (idx + 0 < n) { rs[idx + 0] = e4.x; cursor[idx + 0] = e4.x; }
      if (idx + 1 < n) { rs[idx + 1] = e4.y; cursor[idx + 1] = e4.y; }
      if (idx + 2 < n) { rs[idx + 2] = e4.z; cursor[idx + 2] = e4.z; }
    }
    int tot = 0;
    if (t == 1023) tot = ex + s;
    __syncthreads();            // all carry-reads done before update
    if (t == 1023) carry = tot;
    __syncthreads();
  }
  if (t == 0) rs[n] = carry;
}

__global__ void scatter_kernel(const int* __restrict__ src, const int* __restrict__ dst,
                               int* cursor, int* csr, int n) {
  int e = blockIdx.x * blockDim.x + threadIdx.x;
  if (e < n) {
    int d = dst[e];
    int p = atomicAdd(&cursor[d], 1);
    csr[p] = src[e];
  }
}

__global__ void scatter2_kernel(const int* __restrict__ src, const int* __restrict__ dst,
                                const int* __restrict__ new_id, int* cursor, int* csr, int n) {
  int e = blockIdx.x * blockDim.x + threadIdx.x;
  if (e < n) {
    int a = new_id[src[e]], d = new_id[dst[e]];
    if (a >= 0 && d >= 0) {
      int p = atomicAdd(&cursor[d], 1);
      csr[p] = a;
    }
  }
}

// ---------------- aggregation (gather-sum, float4, XCD-swizzled) ----------------
// block = 256 threads = 4 waves; each wave handles one node; F4 = feature width / 4
template <int F4>
__global__ void agg_kernel(const float4* __restrict__ feat, const int* __restrict__ rs,
                           const int* __restrict__ csr, float4* __restrict__ agg, int M,
                           int nwg) {
  // bijective XCD-chunk swizzle (m204): XCD x gets a contiguous chunk of node space
  int b = blockIdx.x;
  int q = nwg >> 3, r = nwg & 7, x = b & 7, i = b >> 3;
  int swz = (x < r ? x * (q + 1) : r * (q + 1) + (x - r) * q) + i;
  int node = swz * 4 + (threadIdx.x >> 6);
  if (node >= M) return;
  int lane = threadIdx.x & 63;
  int sub = lane / F4, f4 = lane % F4;  // 64/F4 edges in flight per wave
  int e0 = rs[node], e1 = rs[node + 1];
  float4 acc = make_float4(0.f, 0.f, 0.f, 0.f);
  for (int e = e0 + sub; e < e1; e += 64 / F4) {
    float4 v = feat[(size_t)csr[e] * F4 + f4];
    acc.x += v.x; acc.y += v.y; acc.z += v.z; acc.w += v.w;
  }
  // reduce partial sums across subs (valid in lanes with sub==0)
  acc.x += __shfl_down(acc.x, 32, 64);
  acc.y += __shfl_down(acc.y, 32, 64);
  acc.z += __shfl_down(acc.z, 32, 64);
  acc.w += __shfl_down(acc.w, 32, 64);
  if (F4 == 16) {
    acc.x += __shfl_down(acc.x, 16, 64);
    acc.y += __shfl_down(acc.y, 16, 64);
    acc.z += __shfl_down(acc.z, 16, 64);
    acc.w += __shfl_down(acc.w, 16, 64);
  }
  if (sub == 0) agg[(size_t)node * F4 + f4] = acc;
}

// ---------------- fused conv GEMM via f16 split-precision MFMA ----------------
// out = relu([agg|x] @ Wcat^T + b); Wcat pre-split into Wh + Wl (f16), [128][KTOT].
// Error ~2^-22 (3-product hi/lo scheme) — f32-class accuracy.
// Block: 256 threads = 4 waves; each wave computes 16 rows x 128 cols.
template <int KD1, int KD2>
__global__ void conv_mfma(const float* __restrict__ agg, const float* __restrict__ xr,
                          const _Float16* __restrict__ Wh, const _Float16* __restrict__ Wl,
                          const float* __restrict__ bias, float* __restrict__ out, int M) {
  constexpr int KTOT = KD1 + KD2;
  int wid = threadIdx.x >> 6, lane = threadIdx.x & 63;
  int row0 = blockIdx.x * 64 + wid * 16;
  int arow = row0 + (lane & 15);
  if (arow >= M) arow = M - 1;  // clamp: stores are guarded, padded rows never written
  int kgrp = (lane >> 4) * 8;
  int col = lane & 15;

  f32x4 acc[8];
#pragma unroll
  for (int c = 0; c < 8; ++c) acc[c] = (f32x4){0.f, 0.f, 0.f, 0.f};

#pragma unroll 2
  for (int k0 = 0; k0 < KTOT; k0 += 32) {
    int kk = k0 + kgrp;  // wave-uniform branch: KD1 % 32 == 0
    const float* srcp = (kk < KD1) ? (agg + (size_t)arow * KD1 + kk)
                                   : (xr + (size_t)arow * KD2 + (kk - KD1));
    float4 a0 = *(const float4*)srcp;
    float4 a1 = *(const float4*)(srcp + 4);
    float av[8] = {a0.x, a0.y, a0.z, a0.w, a1.x, a1.y, a1.z, a1.w};
    half8 ah, al;
#pragma unroll
    for (int j = 0; j < 8; ++j) {
      _Float16 h = (_Float16)av[j];
      ah[j] = h;
      al[j] = (_Float16)(av[j] - (float)h);
    }
#pragma unroll
    for (int c = 0; c < 8; ++c) {
      size_t wof = (size_t)(c * 16 + col) * KTOT + kk;
      half8 bh = *(const half8*)(Wh + wof);
      half8 bl = *(const half8*)(Wl + wof);
      acc[c] = __builtin_amdgcn_mfma_f32_16x16x32_f16(al, bh, acc[c], 0, 0, 0);
      acc[c] = __builtin_amdgcn_mfma_f32_16x16x32_f16(ah, bl, acc[c], 0, 0, 0);
      acc[c] = __builtin_amdgcn_mfma_f32_16x16x32_f16(ah, bh, acc[c], 0, 0, 0);
    }
  }

  int orow0 = row0 + (lane >> 4) * 4;
#pragma unroll
  for (int c = 0; c < 8; ++c) {
    int ocol = c * 16 + col;
    float bv = bias[ocol];
#pragma unroll
    for (int r = 0; r < 4; ++r) {
      int orow = orow0 + r;
      if (orow < M) out[(size_t)orow * HH + ocol] = fmaxf(acc[c][r] + bv, 0.f);
    }
  }
}

// ---------------- weight prep: split Wcat[o][k] into f16 hi + lo planes ----------------
__global__ void prep_weights_f16(const float* __restrict__ W1_rel, const float* __restrict__ W1_root,
                                 const float* __restrict__ W2_rel, const float* __restrict__ W2_root,
                                 const float* __restrict__ W3_rel, const float* __restrict__ W3_root,
                                 _Float16* wh1, _Float16* wl1, _Float16* wh2, _Float16* wl2,
                                 _Float16* wh3, _Float16* wl3) {
  int idx = blockIdx.x * blockDim.x + threadIdx.x;
  float v;
  _Float16* ph;
  _Float16* pl;
  int j;
  if (idx < 128 * 128) {
    j = idx;
    int o = j >> 7, k = j & 127;
    v = (k < 64) ? W1_rel[o * 64 + k] : W1_root[o * 64 + (k - 64)];
    ph = wh1; pl = wl1;
  } else if (idx < 128 * 128 + 128 * 256) {
    j = idx - 128 * 128;
    int o = j >> 8, k = j & 255;
    v = (k < 128) ? W2_rel[o * 128 + k] : W2_root[o * 128 + (k - 128)];
    ph = wh2; pl = wl2;
  } else if (idx < 128 * 128 + 2 * 128 * 256) {
    j = idx - 128 * 128 - 128 * 256;
    int o = j >> 8, k = j & 255;
    v = (k < 128) ? W3_rel[o * 128 + k] : W3_root[o * 128 + (k - 128)];
    ph = wh3; pl = wl3;
  } else {
    return;
  }
  _Float16 h = (_Float16)v;
  ph[j] = h;
  pl[j] = (_Float16)(v - (float)h);
}

// ---------------- pooling partials ----------------
__global__ void pool_partial_kernel(const float* __restrict__ h, int rows_per_graph,
                                    float* pmax, float* psum) {
  int b = blockIdx.x / SLICES, s = blockIdx.x % SLICES;
  int f = threadIdx.x;
  int per = (rows_per_graph + SLICES - 1) / SLICES;
  int r0 = s * per, r1 = min(rows_per_graph, r0 + per);
  float m = -3.402823466e38f, sum = 0.f;
  for (int r = r0; r < r1; ++r) {
    float v = h[(size_t)(b * rows_per_graph + r) * HH + f];
    m = fmaxf(m, v);
    sum += v;
  }
  pmax[(b * SLICES + s) * HH + f] = m;
  psum[(b * SLICES + s) * HH + f] = sum;
}

// ---------------- scoring / topk ----------------
__global__ void norm_kernel(const float* __restrict__ w, float* normv) {
  __shared__ float sd[128];
  int t = threadIdx.x;
  sd[t] = w[t] * w[t];
  __syncthreads();
  for (int off = 64; off > 0; off >>= 1) {
    if (t < off) sd[t] += sd[t + off];
    __syncthreads();
  }
  if (t == 0) normv[0] = sqrtf(sd[0]);
}

__global__ void score_kernel(const float* __restrict__ h2, const float* __restrict__ w,
                             const float* __restrict__ normv, float* score, int M) {
  int wave = threadIdx.x >> 6;
  int lane = threadIdx.x & 63;
  int i = blockIdx.x * (blockDim.x >> 6) + wave;
  if (i >= M) return;
  float acc = h2[i * HH + lane] * w[lane] + h2[i * HH + 64 + lane] * w[64 + lane];
  for (int off = 32; off > 0; off >>= 1) acc += __shfl_down(acc, off, 64);
  if (lane == 0) score[i] = tanhf(acc / normv[0]);
}

// per-graph bitonic sort of 2048 (score,index) keys; keep top K, tie-break lowest index
__global__ void topk_kernel(const float* __restrict__ score, int* perm) {
  __shared__ unsigned long long k[NN];
  int b = blockIdx.x;
  int tid = threadIdx.x;  // 1024
  for (int i = tid; i < NN; i += 1024) {
    float s = score[b * NN + i];
    unsigned u = __float_as_uint(s);
    u = (u & 0x80000000u) ? ~u : (u | 0x80000000u);
    unsigned long long key = ((unsigned long long)u << 32) | (unsigned)(NN - 1 - i);
    k[i] = ~key;  // ascending sort of ~key == descending by (score, -index)
  }
  __syncthreads();
  for (int kk = 2; kk <= NN; kk <<= 1) {
    for (int j = kk >> 1; j > 0; j >>= 1) {
      for (int t = tid; t < NN; t += 1024) {
        int ixj = t ^ j;
        if (ixj > t) {
          bool up = ((t & kk) == 0);
          unsigned long long a = k[t], c = k[ixj];
          if ((a > c) == up) { k[t] = c; k[ixj] = a; }
        }
      }
      __syncthreads();
    }
  }
  for (int j = tid; j < KK; j += 1024) {
    unsigned long long key = ~k[j];
    int i = (NN - 1) - (int)(key & 0xffffffffu);
    perm[b * KK + j] = b * NN + i;
  }
}

// gather kept rows, scale by score, and write new_id (fused)
__global__ void h3_kernel(const float4* __restrict__ h2, const int* __restrict__ perm,
                          const float* __restrict__ score, float4* __restrict__ h3,
                          int* new_id) {
  int idx = blockIdx.x * blockDim.x + threadIdx.x;  // over N1*32 float4s
  if (idx < N1 * 32) {
    int g = idx >> 5, c = idx & 31;
    int p = perm[g];
    if (c == 0) new_id[p] = g;
    float s = score[p];
    float4 v = h2[(size_t)p * 32 + c];
    v.x *= s; v.y *= s; v.z *= s; v.w *= s;
    h3[idx] = v;
  }
}

// ---------------- final: pool-final x3 + MLP + log_softmax ----------------
__global__ void mlp_kernel(const float* __restrict__ pm1, const float* __restrict__ ps1,
                           const float* __restrict__ pm2, const float* __restrict__ ps2,
                           const float* __restrict__ pm3, const float* __restrict__ ps3,
                           const float* __restrict__ Wl1, const float* __restrict__ bl1,
                           const float* __restrict__ Wl2, const float* __restrict__ bl2,
                           const float* __restrict__ Wl3, const float* __restrict__ bl3,
                           float* out) {
  __shared__ float z[256], a1[128], a2[64], a3[10], red[2];
  int b = blockIdx.x, t = threadIdx.x;  // 128 threads
  float m1 = -3.402823466e38f, m2 = m1, m3 = m1;
  float s1 = 0.f, s2 = 0.f, s3 = 0.f;
  for (int s = 0; s < SLICES; ++s) {
    int o = (b * SLICES + s) * 128 + t;
    m1 = fmaxf(m1, pm1[o]); s1 += ps1[o];
    m2 = fmaxf(m2, pm2[o]); s2 += ps2[o];
    m3 = fmaxf(m3, pm3[o]); s3 += ps3[o];
  }
  z[t] = m1 + m2 + m3;
  z[128 + t] = s1 * (1.f / NN) + (s2 + s3) * (1.f / KK);
  __syncthreads();
  {
    float acc = bl1[t];
    for (int q = 0; q < 256; ++q) acc = fmaf(Wl1[t * 256 + q], z[q], acc);
    a1[t] = fmaxf(acc, 0.f);
  }
  __syncthreads();
  if (t < 64) {
    float acc = bl2[t];
    for (int q = 0; q < 128; ++q) acc = fmaf(Wl2[t * 128 + q], a1[q], acc);
    a2[t] = fmaxf(acc, 0.f);
  }
  __syncthreads();
  if (t < 10) {
    float acc = bl3[t];
    for (int q = 0; q < 64; ++q) acc = fmaf(Wl3[t * 64 + q], a2[q], acc);
    a3[t] = acc;
  }
  __syncthreads();
  if (t == 0) {
    float m = a3[0];
    for (int i = 1; i < 10; ++i) m = fmaxf(m, a3[i]);
    float s = 0.f;
    for (int i = 0; i < 10; ++i) s += expf(a3[i] - m);
    red[0] = m;
    red[1] = logf(s);
  }
  __syncthreads();
  if (t < 10) out[b * 10 + t] = a3[t] - red[0] - red[1];
}

extern "C" void kernel_launch(void* const* d_in, const int* in_sizes, int n_in,
                              void* d_out, int out_size, void* d_ws, size_t ws_size,
                              hipStream_t stream) {
  const float* x       = (const float*)d_in[0];
  const int*   src     = (const int*)d_in[1];
  const int*   dst     = (const int*)d_in[2];
  const float* W1_rel  = (const float*)d_in[3];
  const float* b1      = (const float*)d_in[4];
  const float* W1_root = (const float*)d_in[5];
  const float* W2_rel  = (const float*)d_in[6];
  const float* b2      = (const float*)d_in[7];
  const float* W2_root = (const float*)d_in[8];
  const float* W3_rel  = (const float*)d_in[9];
  const float* b3      = (const float*)d_in[10];
  const float* W3_root = (const float*)d_in[11];
  const float* pool_w  = (const float*)d_in[12];
  const float* Wl1     = (const float*)d_in[13];
  const float* bl1     = (const float*)d_in[14];
  const float* Wl2     = (const float*)d_in[15];
  const float* bl2     = (const float*)d_in[16];
  const float* Wl3     = (const float*)d_in[17];
  const float* bl3     = (const float*)d_in[18];
  float* out = (float*)d_out;

  // workspace layout
  char* w = (char*)d_ws;
  size_t off = 0;
  auto alloc = [&](size_t bytes) -> char* {
    off = (off + 255) & ~(size_t)255;
    char* p = w + off;
    off += bytes;
    return p;
  };
  // deg1 | deg2 contiguous (one memset); +4096 ints pad for exscan int4 tiles
  int* degs     = (int*)alloc((NB + N1 + 4096) * 4);
  int* deg1     = degs;
  int* deg2     = degs + NB;
  int* rs1      = (int*)alloc((NB + 1) * 4);
  int* cursor1  = (int*)alloc(NB * 4);
  int* csr1     = (int*)alloc((size_t)EE * 4);
  int* rs2      = (int*)alloc((N1 + 1) * 4);
  int* cursor2  = (int*)alloc(N1 * 4);
  int* csr2     = (int*)alloc((size_t)EE * 4);
  int* new_id   = (int*)alloc(NB * 4);
  int* perm     = (int*)alloc(N1 * 4);
  _Float16* wh1 = (_Float16*)alloc(128 * 128 * 2);
  _Float16* wl1 = (_Float16*)alloc(128 * 128 * 2);
  _Float16* wh2 = (_Float16*)alloc(128 * 256 * 2);
  _Float16* wl2 = (_Float16*)alloc(128 * 256 * 2);
  _Float16* wh3 = (_Float16*)alloc(128 * 256 * 2);
  _Float16* wl3 = (_Float16*)alloc(128 * 256 * 2);
  float* aggbuf = (float*)alloc((size_t)NB * HH * 4);
  float* bufA   = (float*)alloc((size_t)NB * HH * 4);  // h1, then h3
  float* bufB   = (float*)alloc((size_t)NB * HH * 4);  // h2, then h4
  float* score  = (float*)alloc(NB * 4);
  float* normv  = (float*)alloc(64);
  float* pm1    = (float*)alloc(BG * SLICES * HH * 4);
  float* ps1    = (float*)alloc(BG * SLICES * HH * 4);
  float* pm2    = (float*)alloc(BG * SLICES * HH * 4);
  float* ps2    = (float*)alloc(BG * SLICES * HH * 4);
  float* pm3    = (float*)alloc(BG * SLICES * HH * 4);
  float* ps3    = (float*)alloc(BG * SLICES * HH * 4);
  if (off > ws_size) return;  // workspace too small: fail visibly

  const int TB = 256;
  const int egrid = (EE + TB - 1) / TB;

  hipMemsetAsync(degs, 0, (NB + N1 + 4096) * 4, stream);
  hipMemsetAsync(new_id, 0xFF, NB * 4, stream);  // -1

  prep_weights_f16<<<(128 * 128 + 2 * 128 * 256 + TB - 1) / TB, TB, 0, stream>>>(
      W1_rel, W1_root, W2_rel, W2_root, W3_rel, W3_root, wh1, wl1, wh2, wl2, wh3, wl3);

  // CSR1 (src -> dst)
  deg_kernel<<<egrid, TB, 0, stream>>>(dst, deg1, EE);
  exscan_kernel<<<1, 1024, 0, stream>>>(deg1, rs1, cursor1, NB);
  scatter_kernel<<<egrid, TB, 0, stream>>>(src, dst, cursor1, csr1, EE);

  // conv1 (K = 64 agg + 64 root)
  agg_kernel<16><<<NB / 4, 256, 0, stream>>>((const float4*)x, rs1, csr1, (float4*)aggbuf,
                                             NB, NB / 4);
  conv_mfma<64, 64><<<NB / 64, 256, 0, stream>>>(aggbuf, x, wh1, wl1, b1, bufA, NB);
  pool_partial_kernel<<<BG * SLICES, 128, 0, stream>>>(bufA, NN, pm1, ps1);

  // conv2
  agg_kernel<32><<<NB / 4, 256, 0, stream>>>((const float4*)bufA, rs1, csr1, (float4*)aggbuf,
                                             NB, NB / 4);
  conv_mfma<128, 128><<<NB / 64, 256, 0, stream>>>(aggbuf, bufA, wh2, wl2, b2, bufB, NB);

  // topk
  norm_kernel<<<1, 128, 0, stream>>>(pool_w, normv);
  score_kernel<<<NB / 4, 256, 0, stream>>>(bufB, pool_w, normv, score, NB);
  topk_kernel<<<BG, 1024, 0, stream>>>(score, perm);
  h3_kernel<<<(N1 * 32 + TB - 1) / TB, TB, 0, stream>>>((const float4*)bufB, perm, score,
                                                        (float4*)bufA, new_id);
  pool_partial_kernel<<<BG * SLICES, 128, 0, stream>>>(bufA, KK, pm2, ps2);

  // CSR2 over remapped kept edges
  deg2_kernel<<<egrid, TB, 0, stream>>>(src, dst, new_id, deg2, EE);
  exscan_kernel<<<1, 1024, 0, stream>>>(deg2, rs2, cursor2, N1);
  scatter2_kernel<<<egrid, TB, 0, stream>>>(src, dst, new_id, cursor2, csr2, EE);

  // conv3
  agg_kernel<32><<<(N1 + 3) / 4, 256, 0, stream>>>((const float4*)bufA, rs2, csr2,
                                                   (float4*)aggbuf, N1, (N1 + 3) / 4);
  conv_mfma<128, 128><<<(N1 + 63) / 64, 256, 0, stream>>>(aggbuf, bufA, wh3, wl3, b3, bufB, N1);
  pool_partial_kernel<<<BG * SLICES, 128, 0, stream>>>(bufB, KK, pm3, ps3);

  // pool finals + MLP head + log_softmax (fused)
  mlp_kernel<<<BG, 128, 0, stream>>>(pm1, ps1, pm2, ps2, pm3, ps3,
                                     Wl1, bl1, Wl2, bl2, Wl3, bl3, out);
}

// Round 5
// 428.923 us; speedup vs baseline: 1.5166x; 1.0169x over previous
//
#include <hip/hip_runtime.h>
#include <hip/hip_bf16.h>
#include <math.h>

#define NB 32768      // total nodes (B*N)
#define NN 2048       // nodes per graph
#define BG 16         // graphs
#define KK 1639       // kept per graph
#define N1 (BG*KK)    // 26224 kept nodes total
#define EE 524288     // total edges
#define HH 128        // hidden
#define FIN 64        // input features
#define SLICES 16

using half8 = __attribute__((ext_vector_type(8))) _Float16;
using f32x4 = __attribute__((ext_vector_type(4))) float;

// ---------------- CSR build ----------------
__global__ void deg_kernel(const int* __restrict__ dst, int* deg, int n) {
  int e = blockIdx.x * blockDim.x + threadIdx.x;
  if (e < n) atomicAdd(&deg[dst[e]], 1);
}

__global__ void deg2_kernel(const int* __restrict__ src, const int* __restrict__ dst,
                            const int* __restrict__ new_id, int* deg, int n) {
  int e = blockIdx.x * blockDim.x + threadIdx.x;
  if (e < n) {
    int a = new_id[src[e]], d = new_id[dst[e]];
    if (a >= 0 && d >= 0) atomicAdd(&deg[d], 1);
  }
}

// single-block coalesced exclusive scan over tiles of 4096 (int4/lane);
// writes rs[0..n] and cursor[0..n-1]. Caller must pad deg so int4 reads up to
// ceil(n/4096)*4096 stay in-bounds.
__global__ void exscan_kernel(const int* __restrict__ deg, int* rs, int* cursor, int n) {
  __shared__ int wsum[16];
  __shared__ int carry;
  int t = threadIdx.x;  // 1024
  int lane = t & 63, wid = t >> 6;
  if (t == 0) carry = 0;
  __syncthreads();
  int ntiles = (n + 4095) >> 12;
  for (int tile = 0; tile < ntiles; ++tile) {
    int idx = (tile << 12) + t * 4;
    int4 v4 = *(const int4*)(deg + idx);  // coalesced 16B/lane (padded alloc)
    int v0 = (idx + 0 < n) ? v4.x : 0;
    int v1 = (idx + 1 < n) ? v4.y : 0;
    int v2 = (idx + 2 < n) ? v4.z : 0;
    int v3 = (idx + 3 < n) ? v4.w : 0;
    int s = v0 + v1 + v2 + v3;
    int pre = s;
#pragma unroll
    for (int off = 1; off < 64; off <<= 1) {
      int u = __shfl_up(pre, off, 64);
      if (lane >= off) pre += u;
    }
    if (lane == 63) wsum[wid] = pre;
    __syncthreads();
    int wbase = 0;
#pragma unroll
    for (int ww = 0; ww < 16; ++ww)
      if (ww < wid) wbase += wsum[ww];
    int ex = carry + wbase + (pre - s);
    int4 e4 = make_int4(ex, ex + v0, ex + v0 + v1, ex + v0 + v1 + v2);
    if (idx + 3 < n) {
      *(int4*)(rs + idx) = e4;
      *(int4*)(cursor + idx) = e4;
    } else {
      if (idx + 0 < n) { rs[idx + 0] = e4.x; cursor[idx + 0] = e4.x; }
      if (idx + 1 < n) { rs[idx + 1] = e4.y; cursor[idx + 1] = e4.y; }
      if (idx + 2 < n) { rs[idx + 2] = e4.z; cursor[idx + 2] = e4.z; }
    }
    int tot = 0;
    if (t == 1023) tot = ex + s;
    __syncthreads();            // all carry-reads done before update
    if (t == 1023) carry = tot;
    __syncthreads();
  }
  if (t == 0) rs[n] = carry;
}

__global__ void scatter_kernel(const int* __restrict__ src, const int* __restrict__ dst,
                               int* cursor, int* csr, int n) {
  int e = blockIdx.x * blockDim.x + threadIdx.x;
  if (e < n) {
    int d = dst[e];
    int p = atomicAdd(&cursor[d], 1);
    csr[p] = src[e];
  }
}

__global__ void scatter2_kernel(const int* __restrict__ src, const int* __restrict__ dst,
                                const int* __restrict__ new_id, int* cursor, int* csr, int n) {
  int e = blockIdx.x * blockDim.x + threadIdx.x;
  if (e < n) {
    int a = new_id[src[e]], d = new_id[dst[e]];
    if (a >= 0 && d >= 0) {
      int p = atomicAdd(&cursor[d], 1);
      csr[p] = a;
    }
  }
}

// ---------------- aggregation (gather-sum, float4, XCD-swizzled) ----------------
// block = 256 threads = 4 waves; each wave handles one node; F4 = feature width / 4
template <int F4>
__global__ void agg_kernel(const float4* __restrict__ feat, const int* __restrict__ rs,
                           const int* __restrict__ csr, float4* __restrict__ agg, int M,
                           int nwg) {
  // bijective XCD-chunk swizzle (m204): XCD x gets a contiguous chunk of node space
  int b = blockIdx.x;
  int q = nwg >> 3, r = nwg & 7, x = b & 7, i = b >> 3;
  int swz = (x < r ? x * (q + 1) : r * (q + 1) + (x - r) * q) + i;
  int node = swz * 4 + (threadIdx.x >> 6);
  if (node >= M) return;
  int lane = threadIdx.x & 63;
  int sub = lane / F4, f4 = lane % F4;  // 64/F4 edges in flight per wave
  int e0 = rs[node], e1 = rs[node + 1];
  float4 acc = make_float4(0.f, 0.f, 0.f, 0.f);
  for (int e = e0 + sub; e < e1; e += 64 / F4) {
    float4 v = feat[(size_t)csr[e] * F4 + f4];
    acc.x += v.x; acc.y += v.y; acc.z += v.z; acc.w += v.w;
  }
  // reduce partial sums across subs (valid in lanes with sub==0)
  acc.x += __shfl_down(acc.x, 32, 64);
  acc.y += __shfl_down(acc.y, 32, 64);
  acc.z += __shfl_down(acc.z, 32, 64);
  acc.w += __shfl_down(acc.w, 32, 64);
  if (F4 == 16) {
    acc.x += __shfl_down(acc.x, 16, 64);
    acc.y += __shfl_down(acc.y, 16, 64);
    acc.z += __shfl_down(acc.z, 16, 64);
    acc.w += __shfl_down(acc.w, 16, 64);
  }
  if (sub == 0) agg[(size_t)node * F4 + f4] = acc;
}

// ---------------- fused conv GEMM via f16 split-precision MFMA ----------------
// out = relu([agg|x] @ Wcat^T + b); Wcat pre-split into Wh + Wl (f16), [128][KTOT].
// Error ~2^-22 (3-product hi/lo scheme) — f32-class accuracy.
// Block: 512 threads = 8 waves; wave tile = 16 rows x 64 cols (4 col-frags).
// Grid: (ceil(M/128), 2 col-halves) -> 2x waves vs 16x128 tiling, for latency hiding.
// A prefetched one k-step ahead; k-loop fully unrolled so B loads hoist over MFMAs.
template <int KD1, int KD2>
__global__ __launch_bounds__(512) void conv_mfma(
    const float* __restrict__ agg, const float* __restrict__ xr,
    const _Float16* __restrict__ Wh, const _Float16* __restrict__ Wl,
    const float* __restrict__ bias, float* __restrict__ out, int M) {
  constexpr int KTOT = KD1 + KD2;
  int wid = threadIdx.x >> 6, lane = threadIdx.x & 63;
  int row0 = blockIdx.x * 128 + wid * 16;
  int col0 = blockIdx.y * 64;
  int arow = row0 + (lane & 15);
  if (arow >= M) arow = M - 1;  // clamp: stores are guarded, padded rows never written
  int kgrp = (lane >> 4) * 8;
  int col = lane & 15;

  f32x4 acc[4];
#pragma unroll
  for (int c = 0; c < 4; ++c) acc[c] = (f32x4){0.f, 0.f, 0.f, 0.f};

  // prefetch k-step 0 (always in agg half: KD1 >= 32)
  const float* sp0 = agg + (size_t)arow * KD1 + kgrp;
  float4 a0 = *(const float4*)sp0;
  float4 a1 = *(const float4*)(sp0 + 4);

#pragma unroll
  for (int k0 = 0; k0 < KTOT; k0 += 32) {
    float4 n0, n1;
    if (k0 + 32 < KTOT) {  // compile-time after unroll
      int kn = k0 + 32 + kgrp;  // wave-uniform branch (KD1 % 32 == 0)
      const float* sp = (kn < KD1) ? (agg + (size_t)arow * KD1 + kn)
                                   : (xr + (size_t)arow * KD2 + (kn - KD1));
      n0 = *(const float4*)sp;
      n1 = *(const float4*)(sp + 4);
    }
    float av[8] = {a0.x, a0.y, a0.z, a0.w, a1.x, a1.y, a1.z, a1.w};
    half8 ah, al;
#pragma unroll
    for (int j = 0; j < 8; ++j) {
      _Float16 h = (_Float16)av[j];
      ah[j] = h;
      al[j] = (_Float16)(av[j] - (float)h);
    }
    int kk = k0 + kgrp;
#pragma unroll
    for (int c = 0; c < 4; ++c) {
      size_t wof = (size_t)(col0 + c * 16 + col) * KTOT + kk;
      half8 bh = *(const half8*)(Wh + wof);
      half8 bl = *(const half8*)(Wl + wof);
      acc[c] = __builtin_amdgcn_mfma_f32_16x16x32_f16(al, bh, acc[c], 0, 0, 0);
      acc[c] = __builtin_amdgcn_mfma_f32_16x16x32_f16(ah, bl, acc[c], 0, 0, 0);
      acc[c] = __builtin_amdgcn_mfma_f32_16x16x32_f16(ah, bh, acc[c], 0, 0, 0);
    }
    a0 = n0;
    a1 = n1;
  }

  int orow0 = row0 + (lane >> 4) * 4;
#pragma unroll
  for (int c = 0; c < 4; ++c) {
    int ocol = col0 + c * 16 + col;
    float bv = bias[ocol];
#pragma unroll
    for (int r = 0; r < 4; ++r) {
      int orow = orow0 + r;
      if (orow < M) out[(size_t)orow * HH + ocol] = fmaxf(acc[c][r] + bv, 0.f);
    }
  }
}

// ---------------- weight prep: split Wcat[o][k] into f16 hi + lo planes ----------------
__global__ void prep_weights_f16(const float* __restrict__ W1_rel, const float* __restrict__ W1_root,
                                 const float* __restrict__ W2_rel, const float* __restrict__ W2_root,
                                 const float* __restrict__ W3_rel, const float* __restrict__ W3_root,
                                 _Float16* wh1, _Float16* wl1, _Float16* wh2, _Float16* wl2,
                                 _Float16* wh3, _Float16* wl3) {
  int idx = blockIdx.x * blockDim.x + threadIdx.x;
  float v;
  _Float16* ph;
  _Float16* pl;
  int j;
  if (idx < 128 * 128) {
    j = idx;
    int o = j >> 7, k = j & 127;
    v = (k < 64) ? W1_rel[o * 64 + k] : W1_root[o * 64 + (k - 64)];
    ph = wh1; pl = wl1;
  } else if (idx < 128 * 128 + 128 * 256) {
    j = idx - 128 * 128;
    int o = j >> 8, k = j & 255;
    v = (k < 128) ? W2_rel[o * 128 + k] : W2_root[o * 128 + (k - 128)];
    ph = wh2; pl = wl2;
  } else if (idx < 128 * 128 + 2 * 128 * 256) {
    j = idx - 128 * 128 - 128 * 256;
    int o = j >> 8, k = j & 255;
    v = (k < 128) ? W3_rel[o * 128 + k] : W3_root[o * 128 + (k - 128)];
    ph = wh3; pl = wl3;
  } else {
    return;
  }
  _Float16 h = (_Float16)v;
  ph[j] = h;
  pl[j] = (_Float16)(v - (float)h);
}

// ---------------- pooling partials ----------------
__global__ void pool_partial_kernel(const float* __restrict__ h, int rows_per_graph,
                                    float* pmax, float* psum) {
  int b = blockIdx.x / SLICES, s = blockIdx.x % SLICES;
  int f = threadIdx.x;
  int per = (rows_per_graph + SLICES - 1) / SLICES;
  int r0 = s * per, r1 = min(rows_per_graph, r0 + per);
  float m = -3.402823466e38f, sum = 0.f;
  for (int r = r0; r < r1; ++r) {
    float v = h[(size_t)(b * rows_per_graph + r) * HH + f];
    m = fmaxf(m, v);
    sum += v;
  }
  pmax[(b * SLICES + s) * HH + f] = m;
  psum[(b * SLICES + s) * HH + f] = sum;
}

// ---------------- scoring / topk ----------------
__global__ void norm_kernel(const float* __restrict__ w, float* normv) {
  __shared__ float sd[128];
  int t = threadIdx.x;
  sd[t] = w[t] * w[t];
  __syncthreads();
  for (int off = 64; off > 0; off >>= 1) {
    if (t < off) sd[t] += sd[t + off];
    __syncthreads();
  }
  if (t == 0) normv[0] = sqrtf(sd[0]);
}

__global__ void score_kernel(const float* __restrict__ h2, const float* __restrict__ w,
                             const float* __restrict__ normv, float* score, int M) {
  int wave = threadIdx.x >> 6;
  int lane = threadIdx.x & 63;
  int i = blockIdx.x * (blockDim.x >> 6) + wave;
  if (i >= M) return;
  float acc = h2[i * HH + lane] * w[lane] + h2[i * HH + 64 + lane] * w[64 + lane];
  for (int off = 32; off > 0; off >>= 1) acc += __shfl_down(acc, off, 64);
  if (lane == 0) score[i] = tanhf(acc / normv[0]);
}

// per-graph bitonic sort of 2048 (score,index) keys; keep top K, tie-break lowest index
__global__ void topk_kernel(const float* __restrict__ score, int* perm) {
  __shared__ unsigned long long k[NN];
  int b = blockIdx.x;
  int tid = threadIdx.x;  // 1024
  for (int i = tid; i < NN; i += 1024) {
    float s = score[b * NN + i];
    unsigned u = __float_as_uint(s);
    u = (u & 0x80000000u) ? ~u : (u | 0x80000000u);
    unsigned long long key = ((unsigned long long)u << 32) | (unsigned)(NN - 1 - i);
    k[i] = ~key;  // ascending sort of ~key == descending by (score, -index)
  }
  __syncthreads();
  for (int kk = 2; kk <= NN; kk <<= 1) {
    for (int j = kk >> 1; j > 0; j >>= 1) {
      for (int t = tid; t < NN; t += 1024) {
        int ixj = t ^ j;
        if (ixj > t) {
          bool up = ((t & kk) == 0);
          unsigned long long a = k[t], c = k[ixj];
          if ((a > c) == up) { k[t] = c; k[ixj] = a; }
        }
      }
      __syncthreads();
    }
  }
  for (int j = tid; j < KK; j += 1024) {
    unsigned long long key = ~k[j];
    int i = (NN - 1) - (int)(key & 0xffffffffu);
    perm[b * KK + j] = b * NN + i;
  }
}

// gather kept rows, scale by score, and write new_id (fused)
__global__ void h3_kernel(const float4* __restrict__ h2, const int* __restrict__ perm,
                          const float* __restrict__ score, float4* __restrict__ h3,
                          int* new_id) {
  int idx = blockIdx.x * blockDim.x + threadIdx.x;  // over N1*32 float4s
  if (idx < N1 * 32) {
    int g = idx >> 5, c = idx & 31;
    int p = perm[g];
    if (c == 0) new_id[p] = g;
    float s = score[p];
    float4 v = h2[(size_t)p * 32 + c];
    v.x *= s; v.y *= s; v.z *= s; v.w *= s;
    h3[idx] = v;
  }
}

// ---------------- final: pool-final x3 + MLP + log_softmax ----------------
__global__ void mlp_kernel(const float* __restrict__ pm1, const float* __restrict__ ps1,
                           const float* __restrict__ pm2, const float* __restrict__ ps2,
                           const float* __restrict__ pm3, const float* __restrict__ ps3,
                           const float* __restrict__ Wl1, const float* __restrict__ bl1,
                           const float* __restrict__ Wl2, const float* __restrict__ bl2,
                           const float* __restrict__ Wl3, const float* __restrict__ bl3,
                           float* out) {
  __shared__ float z[256], a1[128], a2[64], a3[10], red[2];
  int b = blockIdx.x, t = threadIdx.x;  // 128 threads
  float m1 = -3.402823466e38f, m2 = m1, m3 = m1;
  float s1 = 0.f, s2 = 0.f, s3 = 0.f;
  for (int s = 0; s < SLICES; ++s) {
    int o = (b * SLICES + s) * 128 + t;
    m1 = fmaxf(m1, pm1[o]); s1 += ps1[o];
    m2 = fmaxf(m2, pm2[o]); s2 += ps2[o];
    m3 = fmaxf(m3, pm3[o]); s3 += ps3[o];
  }
  z[t] = m1 + m2 + m3;
  z[128 + t] = s1 * (1.f / NN) + (s2 + s3) * (1.f / KK);
  __syncthreads();
  {
    float acc = bl1[t];
    for (int q = 0; q < 256; ++q) acc = fmaf(Wl1[t * 256 + q], z[q], acc);
    a1[t] = fmaxf(acc, 0.f);
  }
  __syncthreads();
  if (t < 64) {
    float acc = bl2[t];
    for (int q = 0; q < 128; ++q) acc = fmaf(Wl2[t * 128 + q], a1[q], acc);
    a2[t] = fmaxf(acc, 0.f);
  }
  __syncthreads();
  if (t < 10) {
    float acc = bl3[t];
    for (int q = 0; q < 64; ++q) acc = fmaf(Wl3[t * 64 + q], a2[q], acc);
    a3[t] = acc;
  }
  __syncthreads();
  if (t == 0) {
    float m = a3[0];
    for (int i = 1; i < 10; ++i) m = fmaxf(m, a3[i]);
    float s = 0.f;
    for (int i = 0; i < 10; ++i) s += expf(a3[i] - m);
    red[0] = m;
    red[1] = logf(s);
  }
  __syncthreads();
  if (t < 10) out[b * 10 + t] = a3[t] - red[0] - red[1];
}

extern "C" void kernel_launch(void* const* d_in, const int* in_sizes, int n_in,
                              void* d_out, int out_size, void* d_ws, size_t ws_size,
                              hipStream_t stream) {
  const float* x       = (const float*)d_in[0];
  const int*   src     = (const int*)d_in[1];
  const int*   dst     = (const int*)d_in[2];
  const float* W1_rel  = (const float*)d_in[3];
  const float* b1      = (const float*)d_in[4];
  const float* W1_root = (const float*)d_in[5];
  const float* W2_rel  = (const float*)d_in[6];
  const float* b2      = (const float*)d_in[7];
  const float* W2_root = (const float*)d_in[8];
  const float* W3_rel  = (const float*)d_in[9];
  const float* b3      = (const float*)d_in[10];
  const float* W3_root = (const float*)d_in[11];
  const float* pool_w  = (const float*)d_in[12];
  const float* Wl1     = (const float*)d_in[13];
  const float* bl1     = (const float*)d_in[14];
  const float* Wl2     = (const float*)d_in[15];
  const float* bl2     = (const float*)d_in[16];
  const float* Wl3     = (const float*)d_in[17];
  const float* bl3     = (const float*)d_in[18];
  float* out = (float*)d_out;

  // workspace layout
  char* w = (char*)d_ws;
  size_t off = 0;
  auto alloc = [&](size_t bytes) -> char* {
    off = (off + 255) & ~(size_t)255;
    char* p = w + off;
    off += bytes;
    return p;
  };
  // deg1 | deg2 contiguous (one memset); +4096 ints pad for exscan int4 tiles
  int* degs     = (int*)alloc((NB + N1 + 4096) * 4);
  int* deg1     = degs;
  int* deg2     = degs + NB;
  int* rs1      = (int*)alloc((NB + 1) * 4);
  int* cursor1  = (int*)alloc(NB * 4);
  int* csr1     = (int*)alloc((size_t)EE * 4);
  int* rs2      = (int*)alloc((N1 + 1) * 4);
  int* cursor2  = (int*)alloc(N1 * 4);
  int* csr2     = (int*)alloc((size_t)EE * 4);
  int* new_id   = (int*)alloc(NB * 4);
  int* perm     = (int*)alloc(N1 * 4);
  _Float16* wh1 = (_Float16*)alloc(128 * 128 * 2);
  _Float16* wl1 = (_Float16*)alloc(128 * 128 * 2);
  _Float16* wh2 = (_Float16*)alloc(128 * 256 * 2);
  _Float16* wl2 = (_Float16*)alloc(128 * 256 * 2);
  _Float16* wh3 = (_Float16*)alloc(128 * 256 * 2);
  _Float16* wl3 = (_Float16*)alloc(128 * 256 * 2);
  float* aggbuf = (float*)alloc((size_t)NB * HH * 4);
  float* bufA   = (float*)alloc((size_t)NB * HH * 4);  // h1, then h3
  float* bufB   = (float*)alloc((size_t)NB * HH * 4);  // h2, then h4
  float* score  = (float*)alloc(NB * 4);
  float* normv  = (float*)alloc(64);
  float* pm1    = (float*)alloc(BG * SLICES * HH * 4);
  float* ps1    = (float*)alloc(BG * SLICES * HH * 4);
  float* pm2    = (float*)alloc(BG * SLICES * HH * 4);
  float* ps2    = (float*)alloc(BG * SLICES * HH * 4);
  float* pm3    = (float*)alloc(BG * SLICES * HH * 4);
  float* ps3    = (float*)alloc(BG * SLICES * HH * 4);
  if (off > ws_size) return;  // workspace too small: fail visibly

  const int TB = 256;
  const int egrid = (EE + TB - 1) / TB;

  hipMemsetAsync(degs, 0, (NB + N1 + 4096) * 4, stream);
  hipMemsetAsync(new_id, 0xFF, NB * 4, stream);  // -1

  prep_weights_f16<<<(128 * 128 + 2 * 128 * 256 + TB - 1) / TB, TB, 0, stream>>>(
      W1_rel, W1_root, W2_rel, W2_root, W3_rel, W3_root, wh1, wl1, wh2, wl2, wh3, wl3);

  // CSR1 (src -> dst)
  deg_kernel<<<egrid, TB, 0, stream>>>(dst, deg1, EE);
  exscan_kernel<<<1, 1024, 0, stream>>>(deg1, rs1, cursor1, NB);
  scatter_kernel<<<egrid, TB, 0, stream>>>(src, dst, cursor1, csr1, EE);

  // conv1 (K = 64 agg + 64 root)
  agg_kernel<16><<<NB / 4, 256, 0, stream>>>((const float4*)x, rs1, csr1, (float4*)aggbuf,
                                             NB, NB / 4);
  conv_mfma<64, 64><<<dim3(NB / 128, 2), 512, 0, stream>>>(aggbuf, x, wh1, wl1, b1, bufA, NB);
  pool_partial_kernel<<<BG * SLICES, 128, 0, stream>>>(bufA, NN, pm1, ps1);

  // conv2
  agg_kernel<32><<<NB / 4, 256, 0, stream>>>((const float4*)bufA, rs1, csr1, (float4*)aggbuf,
                                             NB, NB / 4);
  conv_mfma<128, 128><<<dim3(NB / 128, 2), 512, 0, stream>>>(aggbuf, bufA, wh2, wl2, b2, bufB,
                                                             NB);

  // topk
  norm_kernel<<<1, 128, 0, stream>>>(pool_w, normv);
  score_kernel<<<NB / 4, 256, 0, stream>>>(bufB, pool_w, normv, score, NB);
  topk_kernel<<<BG, 1024, 0, stream>>>(score, perm);
  h3_kernel<<<(N1 * 32 + TB - 1) / TB, TB, 0, stream>>>((const float4*)bufB, perm, score,
                                                        (float4*)bufA, new_id);
  pool_partial_kernel<<<BG * SLICES, 128, 0, stream>>>(bufA, KK, pm2, ps2);

  // CSR2 over remapped kept edges
  deg2_kernel<<<egrid, TB, 0, stream>>>(src, dst, new_id, deg2, EE);
  exscan_kernel<<<1, 1024, 0, stream>>>(deg2, rs2, cursor2, N1);
  scatter2_kernel<<<egrid, TB, 0, stream>>>(src, dst, new_id, cursor2, csr2, EE);

  // conv3
  agg_kernel<32><<<(N1 + 3) / 4, 256, 0, stream>>>((const float4*)bufA, rs2, csr2,
                                                   (float4*)aggbuf, N1, (N1 + 3) / 4);
  conv_mfma<128, 128><<<dim3((N1 + 127) / 128, 2), 512, 0, stream>>>(aggbuf, bufA, wh3, wl3,
                                                                     b3, bufB, N1);
  pool_partial_kernel<<<BG * SLICES, 128, 0, stream>>>(bufB, KK, pm3, ps3);

  // pool finals + MLP head + log_softmax (fused)
  mlp_kernel<<<BG, 128, 0, stream>>>(pm1, ps1, pm2, ps2, pm3, ps3,
                                     Wl1, bl1, Wl2, bl2, Wl3, bl3, out);
}

// Round 6
// 405.396 us; speedup vs baseline: 1.6046x; 1.0580x over previous
//
#include <hip/hip_runtime.h>
#include <hip/hip_bf16.h>
#include <math.h>

#define NB 32768      // total nodes (B*N)
#define NN 2048       // nodes per graph
#define BG 16         // graphs
#define KK 1639       // kept per graph
#define N1 (BG*KK)    // 26224 kept nodes total
#define EE 524288     // total edges
#define HH 128        // hidden
#define FIN 64        // input features
#define SLICES 16

using half8 = __attribute__((ext_vector_type(8))) _Float16;
using f32x4 = __attribute__((ext_vector_type(4))) float;

// ---------------- CSR build ----------------
__global__ void deg_kernel(const int* __restrict__ dst, int* deg, int n) {
  int e = blockIdx.x * blockDim.x + threadIdx.x;
  if (e < n) atomicAdd(&deg[dst[e]], 1);
}

__global__ void deg2_kernel(const int* __restrict__ src, const int* __restrict__ dst,
                            const int* __restrict__ new_id, int* deg, int n) {
  int e = blockIdx.x * blockDim.x + threadIdx.x;
  if (e < n) {
    int a = new_id[src[e]], d = new_id[dst[e]];
    if (a >= 0 && d >= 0) atomicAdd(&deg[d], 1);
  }
}

// single-block coalesced exclusive scan over tiles of 4096 (int4/lane);
// writes rs[0..n] and cursor[0..n-1]. Caller must pad deg so int4 reads up to
// ceil(n/4096)*4096 stay in-bounds.
__global__ void exscan_kernel(const int* __restrict__ deg, int* rs, int* cursor, int n) {
  __shared__ int wsum[16];
  __shared__ int carry;
  int t = threadIdx.x;  // 1024
  int lane = t & 63, wid = t >> 6;
  if (t == 0) carry = 0;
  __syncthreads();
  int ntiles = (n + 4095) >> 12;
  for (int tile = 0; tile < ntiles; ++tile) {
    int idx = (tile << 12) + t * 4;
    int4 v4 = *(const int4*)(deg + idx);  // coalesced 16B/lane (padded alloc)
    int v0 = (idx + 0 < n) ? v4.x : 0;
    int v1 = (idx + 1 < n) ? v4.y : 0;
    int v2 = (idx + 2 < n) ? v4.z : 0;
    int v3 = (idx + 3 < n) ? v4.w : 0;
    int s = v0 + v1 + v2 + v3;
    int pre = s;
#pragma unroll
    for (int off = 1; off < 64; off <<= 1) {
      int u = __shfl_up(pre, off, 64);
      if (lane >= off) pre += u;
    }
    if (lane == 63) wsum[wid] = pre;
    __syncthreads();
    int wbase = 0;
#pragma unroll
    for (int ww = 0; ww < 16; ++ww)
      if (ww < wid) wbase += wsum[ww];
    int ex = carry + wbase + (pre - s);
    int4 e4 = make_int4(ex, ex + v0, ex + v0 + v1, ex + v0 + v1 + v2);
    if (idx + 3 < n) {
      *(int4*)(rs + idx) = e4;
      *(int4*)(cursor + idx) = e4;
    } else {
      if (idx + 0 < n) { rs[idx + 0] = e4.x; cursor[idx + 0] = e4.x; }
      if (idx + 1 < n) { rs[idx + 1] = e4.y; cursor[idx + 1] = e4.y; }
      if (idx + 2 < n) { rs[idx + 2] = e4.z; cursor[idx + 2] = e4.z; }
    }
    int tot = 0;
    if (t == 1023) tot = ex + s;
    __syncthreads();            // all carry-reads done before update
    if (t == 1023) carry = tot;
    __syncthreads();
  }
  if (t == 0) rs[n] = carry;
}

__global__ void scatter_kernel(const int* __restrict__ src, const int* __restrict__ dst,
                               int* cursor, int* csr, int n) {
  int e = blockIdx.x * blockDim.x + threadIdx.x;
  if (e < n) {
    int d = dst[e];
    int p = atomicAdd(&cursor[d], 1);
    csr[p] = src[e];
  }
}

__global__ void scatter2_kernel(const int* __restrict__ src, const int* __restrict__ dst,
                                const int* __restrict__ new_id, int* cursor, int* csr, int n) {
  int e = blockIdx.x * blockDim.x + threadIdx.x;
  if (e < n) {
    int a = new_id[src[e]], d = new_id[dst[e]];
    if (a >= 0 && d >= 0) {
      int p = atomicAdd(&cursor[d], 1);
      csr[p] = a;
    }
  }
}

// ---------------- aggregation (gather-sum, float4, XCD-swizzled) ----------------
// block = 256 threads = 4 waves; each wave handles one node; F4 = feature width / 4
template <int F4>
__global__ void agg_kernel(const float4* __restrict__ feat, const int* __restrict__ rs,
                           const int* __restrict__ csr, float4* __restrict__ agg, int M,
                           int nwg) {
  // bijective XCD-chunk swizzle (m204): XCD x gets a contiguous chunk of node space
  int b = blockIdx.x;
  int q = nwg >> 3, r = nwg & 7, x = b & 7, i = b >> 3;
  int swz = (x < r ? x * (q + 1) : r * (q + 1) + (x - r) * q) + i;
  int node = swz * 4 + (threadIdx.x >> 6);
  if (node >= M) return;
  int lane = threadIdx.x & 63;
  int sub = lane / F4, f4 = lane % F4;  // 64/F4 edges in flight per wave
  int e0 = rs[node], e1 = rs[node + 1];
  float4 acc = make_float4(0.f, 0.f, 0.f, 0.f);
  for (int e = e0 + sub; e < e1; e += 64 / F4) {
    float4 v = feat[(size_t)csr[e] * F4 + f4];
    acc.x += v.x; acc.y += v.y; acc.z += v.z; acc.w += v.w;
  }
  // reduce partial sums across subs (valid in lanes with sub==0)
  acc.x += __shfl_down(acc.x, 32, 64);
  acc.y += __shfl_down(acc.y, 32, 64);
  acc.z += __shfl_down(acc.z, 32, 64);
  acc.w += __shfl_down(acc.w, 32, 64);
  if (F4 == 16) {
    acc.x += __shfl_down(acc.x, 16, 64);
    acc.y += __shfl_down(acc.y, 16, 64);
    acc.z += __shfl_down(acc.z, 16, 64);
    acc.w += __shfl_down(acc.w, 16, 64);
  }
  if (sub == 0) agg[(size_t)node * F4 + f4] = acc;
}

// ---------------- fused conv GEMM via f16 split-precision MFMA ----------------
// out = relu([agg|x] @ Wcat^T + b); Wcat pre-split into Wh + Wl (f16), [128][KTOT].
// Block: 512 thr = 8 waves; block tile = 16 rows x 128 cols; wave = 16x16.
// W register-stationary (64 VGPR for full K) -> zero B loads in k-loop.
// A staged once to LDS, pre-split f16 hi/lo planes, XOR-swizzled (G4):
// k-loop = 2 ds_read_b128 + 3 MFMA per step, no cvt chain, no global loads.
// Requires M % 16 == 0 (true: 32768, 26224=16*1639).
template <int KD1, int KD2>
__global__ __launch_bounds__(512) void conv_mfma(
    const float* __restrict__ agg, const float* __restrict__ xr,
    const _Float16* __restrict__ Wh, const _Float16* __restrict__ Wl,
    const float* __restrict__ bias, float* __restrict__ out) {
  constexpr int KTOT = KD1 + KD2;
  constexpr int NSTEP = KTOT / 32;
  __shared__ _Float16 ah_lds[16 * KTOT];
  __shared__ _Float16 al_lds[16 * KTOT];

  int tid = threadIdx.x;
  int lane = tid & 63, wid = tid >> 6;
  int row0 = blockIdx.x * 16;
  int ch0 = wid * 16;           // 8 waves cover the 128 output cols
  int col = lane & 15;
  int kseg = (lane >> 4) * 8;

  // ---- W preload: full-K B fragments into registers (static indexing) ----
  half8 wh_r[NSTEP], wl_r[NSTEP];
#pragma unroll
  for (int s = 0; s < NSTEP; ++s) {
    size_t wof = (size_t)(ch0 + col) * KTOT + s * 32 + kseg;
    wh_r[s] = *(const half8*)(Wh + wof);
    wl_r[s] = *(const half8*)(Wl + wof);
  }

  // ---- stage A panel: 16 rows x KTOT f32 -> hi/lo f16 LDS planes ----
  for (int idx = tid; idx < 16 * KTOT / 8; idx += 512) {
    int row = idx / (KTOT / 8);
    int kc = (idx % (KTOT / 8)) * 8;  // 8-elem chunk, never crosses KD1 (both %64==0)
    int grow = row0 + row;
    const float* sp = (kc < KD1) ? (agg + (size_t)grow * KD1 + kc)
                                 : (xr + (size_t)grow * KD2 + (kc - KD1));
    float4 a0 = *(const float4*)sp;
    float4 a1 = *(const float4*)(sp + 4);
    float av[8] = {a0.x, a0.y, a0.z, a0.w, a1.x, a1.y, a1.z, a1.w};
    half8 vh, vl;
#pragma unroll
    for (int j = 0; j < 8; ++j) {
      _Float16 h = (_Float16)av[j];
      vh[j] = h;
      vl[j] = (_Float16)(av[j] - (float)h);
    }
    int byte = ((row * KTOT + kc) * 2) ^ ((row & 7) << 4);
    *(half8*)((char*)ah_lds + byte) = vh;
    *(half8*)((char*)al_lds + byte) = vl;
  }
  __syncthreads();

  // ---- k-loop: pure ds_read + MFMA ----
  f32x4 acc = (f32x4){0.f, 0.f, 0.f, 0.f};
  int r = lane & 15;
  int rbase = r * KTOT * 2;
  int rswz = (r & 7) << 4;
#pragma unroll
  for (int s = 0; s < NSTEP; ++s) {
    int byte = (rbase + (s * 32 + kseg) * 2) ^ rswz;
    half8 a_h = *(const half8*)((const char*)ah_lds + byte);
    half8 a_l = *(const half8*)((const char*)al_lds + byte);
    acc = __builtin_amdgcn_mfma_f32_16x16x32_f16(a_l, wh_r[s], acc, 0, 0, 0);
    acc = __builtin_amdgcn_mfma_f32_16x16x32_f16(a_h, wl_r[s], acc, 0, 0, 0);
    acc = __builtin_amdgcn_mfma_f32_16x16x32_f16(a_h, wh_r[s], acc, 0, 0, 0);
  }

  // ---- epilogue: bias + relu; C/D map col=lane&15, row=(lane>>4)*4+reg ----
  float bv = bias[ch0 + col];
  int orow0 = row0 + (lane >> 4) * 4;
#pragma unroll
  for (int rr = 0; rr < 4; ++rr)
    out[(size_t)(orow0 + rr) * HH + ch0 + col] = fmaxf(acc[rr] + bv, 0.f);
}

// ---------------- weight prep: split Wcat[o][k] into f16 hi + lo planes ----------------
__global__ void prep_weights_f16(const float* __restrict__ W1_rel, const float* __restrict__ W1_root,
                                 const float* __restrict__ W2_rel, const float* __restrict__ W2_root,
                                 const float* __restrict__ W3_rel, const float* __restrict__ W3_root,
                                 _Float16* wh1, _Float16* wl1, _Float16* wh2, _Float16* wl2,
                                 _Float16* wh3, _Float16* wl3) {
  int idx = blockIdx.x * blockDim.x + threadIdx.x;
  float v;
  _Float16* ph;
  _Float16* pl;
  int j;
  if (idx < 128 * 128) {
    j = idx;
    int o = j >> 7, k = j & 127;
    v = (k < 64) ? W1_rel[o * 64 + k] : W1_root[o * 64 + (k - 64)];
    ph = wh1; pl = wl1;
  } else if (idx < 128 * 128 + 128 * 256) {
    j = idx - 128 * 128;
    int o = j >> 8, k = j & 255;
    v = (k < 128) ? W2_rel[o * 128 + k] : W2_root[o * 128 + (k - 128)];
    ph = wh2; pl = wl2;
  } else if (idx < 128 * 128 + 2 * 128 * 256) {
    j = idx - 128 * 128 - 128 * 256;
    int o = j >> 8, k = j & 255;
    v = (k < 128) ? W3_rel[o * 128 + k] : W3_root[o * 128 + (k - 128)];
    ph = wh3; pl = wl3;
  } else {
    return;
  }
  _Float16 h = (_Float16)v;
  ph[j] = h;
  pl[j] = (_Float16)(v - (float)h);
}

// ---------------- pooling partials ----------------
__global__ void pool_partial_kernel(const float* __restrict__ h, int rows_per_graph,
                                    float* pmax, float* psum) {
  int b = blockIdx.x / SLICES, s = blockIdx.x % SLICES;
  int f = threadIdx.x;
  int per = (rows_per_graph + SLICES - 1) / SLICES;
  int r0 = s * per, r1 = min(rows_per_graph, r0 + per);
  float m = -3.402823466e38f, sum = 0.f;
  for (int r = r0; r < r1; ++r) {
    float v = h[(size_t)(b * rows_per_graph + r) * HH + f];
    m = fmaxf(m, v);
    sum += v;
  }
  pmax[(b * SLICES + s) * HH + f] = m;
  psum[(b * SLICES + s) * HH + f] = sum;
}

// ---------------- scoring / topk ----------------
__global__ void norm_kernel(const float* __restrict__ w, float* normv) {
  __shared__ float sd[128];
  int t = threadIdx.x;
  sd[t] = w[t] * w[t];
  __syncthreads();
  for (int off = 64; off > 0; off >>= 1) {
    if (t < off) sd[t] += sd[t + off];
    __syncthreads();
  }
  if (t == 0) normv[0] = sqrtf(sd[0]);
}

__global__ void score_kernel(const float* __restrict__ h2, const float* __restrict__ w,
                             const float* __restrict__ normv, float* score, int M) {
  int wave = threadIdx.x >> 6;
  int lane = threadIdx.x & 63;
  int i = blockIdx.x * (blockDim.x >> 6) + wave;
  if (i >= M) return;
  float acc = h2[i * HH + lane] * w[lane] + h2[i * HH + 64 + lane] * w[64 + lane];
  for (int off = 32; off > 0; off >>= 1) acc += __shfl_down(acc, off, 64);
  if (lane == 0) score[i] = tanhf(acc / normv[0]);
}

// per-graph bitonic sort of 2048 (score,index) keys; keep top K, tie-break lowest index
__global__ void topk_kernel(const float* __restrict__ score, int* perm) {
  __shared__ unsigned long long k[NN];
  int b = blockIdx.x;
  int tid = threadIdx.x;  // 1024
  for (int i = tid; i < NN; i += 1024) {
    float s = score[b * NN + i];
    unsigned u = __float_as_uint(s);
    u = (u & 0x80000000u) ? ~u : (u | 0x80000000u);
    unsigned long long key = ((unsigned long long)u << 32) | (unsigned)(NN - 1 - i);
    k[i] = ~key;  // ascending sort of ~key == descending by (score, -index)
  }
  __syncthreads();
  for (int kk = 2; kk <= NN; kk <<= 1) {
    for (int j = kk >> 1; j > 0; j >>= 1) {
      for (int t = tid; t < NN; t += 1024) {
        int ixj = t ^ j;
        if (ixj > t) {
          bool up = ((t & kk) == 0);
          unsigned long long a = k[t], c = k[ixj];
          if ((a > c) == up) { k[t] = c; k[ixj] = a; }
        }
      }
      __syncthreads();
    }
  }
  for (int j = tid; j < KK; j += 1024) {
    unsigned long long key = ~k[j];
    int i = (NN - 1) - (int)(key & 0xffffffffu);
    perm[b * KK + j] = b * NN + i;
  }
}

// gather kept rows, scale by score, and write new_id (fused)
__global__ void h3_kernel(const float4* __restrict__ h2, const int* __restrict__ perm,
                          const float* __restrict__ score, float4* __restrict__ h3,
                          int* new_id) {
  int idx = blockIdx.x * blockDim.x + threadIdx.x;  // over N1*32 float4s
  if (idx < N1 * 32) {
    int g = idx >> 5, c = idx & 31;
    int p = perm[g];
    if (c == 0) new_id[p] = g;
    float s = score[p];
    float4 v = h2[(size_t)p * 32 + c];
    v.x *= s; v.y *= s; v.z *= s; v.w *= s;
    h3[idx] = v;
  }
}

// ---------------- final: pool-final x3 + MLP + log_softmax ----------------
__global__ void mlp_kernel(const float* __restrict__ pm1, const float* __restrict__ ps1,
                           const float* __restrict__ pm2, const float* __restrict__ ps2,
                           const float* __restrict__ pm3, const float* __restrict__ ps3,
                           const float* __restrict__ Wl1, const float* __restrict__ bl1,
                           const float* __restrict__ Wl2, const float* __restrict__ bl2,
                           const float* __restrict__ Wl3, const float* __restrict__ bl3,
                           float* out) {
  __shared__ float z[256], a1[128], a2[64], a3[10], red[2];
  int b = blockIdx.x, t = threadIdx.x;  // 128 threads
  float m1 = -3.402823466e38f, m2 = m1, m3 = m1;
  float s1 = 0.f, s2 = 0.f, s3 = 0.f;
  for (int s = 0; s < SLICES; ++s) {
    int o = (b * SLICES + s) * 128 + t;
    m1 = fmaxf(m1, pm1[o]); s1 += ps1[o];
    m2 = fmaxf(m2, pm2[o]); s2 += ps2[o];
    m3 = fmaxf(m3, pm3[o]); s3 += ps3[o];
  }
  z[t] = m1 + m2 + m3;
  z[128 + t] = s1 * (1.f / NN) + (s2 + s3) * (1.f / KK);
  __syncthreads();
  {
    float acc = bl1[t];
    for (int q = 0; q < 256; ++q) acc = fmaf(Wl1[t * 256 + q], z[q], acc);
    a1[t] = fmaxf(acc, 0.f);
  }
  __syncthreads();
  if (t < 64) {
    float acc = bl2[t];
    for (int q = 0; q < 128; ++q) acc = fmaf(Wl2[t * 128 + q], a1[q], acc);
    a2[t] = fmaxf(acc, 0.f);
  }
  __syncthreads();
  if (t < 10) {
    float acc = bl3[t];
    for (int q = 0; q < 64; ++q) acc = fmaf(Wl3[t * 64 + q], a2[q], acc);
    a3[t] = acc;
  }
  __syncthreads();
  if (t == 0) {
    float m = a3[0];
    for (int i = 1; i < 10; ++i) m = fmaxf(m, a3[i]);
    float s = 0.f;
    for (int i = 0; i < 10; ++i) s += expf(a3[i] - m);
    red[0] = m;
    red[1] = logf(s);
  }
  __syncthreads();
  if (t < 10) out[b * 10 + t] = a3[t] - red[0] - red[1];
}

extern "C" void kernel_launch(void* const* d_in, const int* in_sizes, int n_in,
                              void* d_out, int out_size, void* d_ws, size_t ws_size,
                              hipStream_t stream) {
  const float* x       = (const float*)d_in[0];
  const int*   src     = (const int*)d_in[1];
  const int*   dst     = (const int*)d_in[2];
  const float* W1_rel  = (const float*)d_in[3];
  const float* b1      = (const float*)d_in[4];
  const float* W1_root = (const float*)d_in[5];
  const float* W2_rel  = (const float*)d_in[6];
  const float* b2      = (const float*)d_in[7];
  const float* W2_root = (const float*)d_in[8];
  const float* W3_rel  = (const float*)d_in[9];
  const float* b3      = (const float*)d_in[10];
  const float* W3_root = (const float*)d_in[11];
  const float* pool_w  = (const float*)d_in[12];
  const float* Wl1     = (const float*)d_in[13];
  const float* bl1     = (const float*)d_in[14];
  const float* Wl2     = (const float*)d_in[15];
  const float* bl2     = (const float*)d_in[16];
  const float* Wl3     = (const float*)d_in[17];
  const float* bl3     = (const float*)d_in[18];
  float* out = (float*)d_out;

  // workspace layout
  char* w = (char*)d_ws;
  size_t off = 0;
  auto alloc = [&](size_t bytes) -> char* {
    off = (off + 255) & ~(size_t)255;
    char* p = w + off;
    off += bytes;
    return p;
  };
  // deg1 | deg2 contiguous (one memset); +4096 ints pad for exscan int4 tiles
  int* degs     = (int*)alloc((NB + N1 + 4096) * 4);
  int* deg1     = degs;
  int* deg2     = degs + NB;
  int* rs1      = (int*)alloc((NB + 1) * 4);
  int* cursor1  = (int*)alloc(NB * 4);
  int* csr1     = (int*)alloc((size_t)EE * 4);
  int* rs2      = (int*)alloc((N1 + 1) * 4);
  int* cursor2  = (int*)alloc(N1 * 4);
  int* csr2     = (int*)alloc((size_t)EE * 4);
  int* new_id   = (int*)alloc(NB * 4);
  int* perm     = (int*)alloc(N1 * 4);
  _Float16* wh1 = (_Float16*)alloc(128 * 128 * 2);
  _Float16* wl1 = (_Float16*)alloc(128 * 128 * 2);
  _Float16* wh2 = (_Float16*)alloc(128 * 256 * 2);
  _Float16* wl2 = (_Float16*)alloc(128 * 256 * 2);
  _Float16* wh3 = (_Float16*)alloc(128 * 256 * 2);
  _Float16* wl3 = (_Float16*)alloc(128 * 256 * 2);
  float* aggbuf = (float*)alloc((size_t)NB * HH * 4);
  float* bufA   = (float*)alloc((size_t)NB * HH * 4);  // h1, then h3
  float* bufB   = (float*)alloc((size_t)NB * HH * 4);  // h2, then h4
  float* score  = (float*)alloc(NB * 4);
  float* normv  = (float*)alloc(64);
  float* pm1    = (float*)alloc(BG * SLICES * HH * 4);
  float* ps1    = (float*)alloc(BG * SLICES * HH * 4);
  float* pm2    = (float*)alloc(BG * SLICES * HH * 4);
  float* ps2    = (float*)alloc(BG * SLICES * HH * 4);
  float* pm3    = (float*)alloc(BG * SLICES * HH * 4);
  float* ps3    = (float*)alloc(BG * SLICES * HH * 4);
  if (off > ws_size) return;  // workspace too small: fail visibly

  const int TB = 256;
  const int egrid = (EE + TB - 1) / TB;

  hipMemsetAsync(degs, 0, (NB + N1 + 4096) * 4, stream);
  hipMemsetAsync(new_id, 0xFF, NB * 4, stream);  // -1

  prep_weights_f16<<<(128 * 128 + 2 * 128 * 256 + TB - 1) / TB, TB, 0, stream>>>(
      W1_rel, W1_root, W2_rel, W2_root, W3_rel, W3_root, wh1, wl1, wh2, wl2, wh3, wl3);

  // CSR1 (src -> dst)
  deg_kernel<<<egrid, TB, 0, stream>>>(dst, deg1, EE);
  exscan_kernel<<<1, 1024, 0, stream>>>(deg1, rs1, cursor1, NB);
  scatter_kernel<<<egrid, TB, 0, stream>>>(src, dst, cursor1, csr1, EE);

  // conv1 (K = 64 agg + 64 root)
  agg_kernel<16><<<NB / 4, 256, 0, stream>>>((const float4*)x, rs1, csr1, (float4*)aggbuf,
                                             NB, NB / 4);
  conv_mfma<64, 64><<<NB / 16, 512, 0, stream>>>(aggbuf, x, wh1, wl1, b1, bufA);
  pool_partial_kernel<<<BG * SLICES, 128, 0, stream>>>(bufA, NN, pm1, ps1);

  // conv2
  agg_kernel<32><<<NB / 4, 256, 0, stream>>>((const float4*)bufA, rs1, csr1, (float4*)aggbuf,
                                             NB, NB / 4);
  conv_mfma<128, 128><<<NB / 16, 512, 0, stream>>>(aggbuf, bufA, wh2, wl2, b2, bufB);

  // topk
  norm_kernel<<<1, 128, 0, stream>>>(pool_w, normv);
  score_kernel<<<NB / 4, 256, 0, stream>>>(bufB, pool_w, normv, score, NB);
  topk_kernel<<<BG, 1024, 0, stream>>>(score, perm);
  h3_kernel<<<(N1 * 32 + TB - 1) / TB, TB, 0, stream>>>((const float4*)bufB, perm, score,
                                                        (float4*)bufA, new_id);
  pool_partial_kernel<<<BG * SLICES, 128, 0, stream>>>(bufA, KK, pm2, ps2);

  // CSR2 over remapped kept edges
  deg2_kernel<<<egrid, TB, 0, stream>>>(src, dst, new_id, deg2, EE);
  exscan_kernel<<<1, 1024, 0, stream>>>(deg2, rs2, cursor2, N1);
  scatter2_kernel<<<egrid, TB, 0, stream>>>(src, dst, new_id, cursor2, csr2, EE);

  // conv3
  agg_kernel<32><<<(N1 + 3) / 4, 256, 0, stream>>>((const float4*)bufA, rs2, csr2,
                                                   (float4*)aggbuf, N1, (N1 + 3) / 4);
  conv_mfma<128, 128><<<N1 / 16, 512, 0, stream>>>(aggbuf, bufA, wh3, wl3, b3, bufB);
  pool_partial_kernel<<<BG * SLICES, 128, 0, stream>>>(bufB, KK, pm3, ps3);

  // pool finals + MLP head + log_softmax (fused)
  mlp_kernel<<<BG, 128, 0, stream>>>(pm1, ps1, pm2, ps2, pm3, ps3,
                                     Wl1, bl1, Wl2, bl2, Wl3, bl3, out);
}

// Round 7
// 362.412 us; speedup vs baseline: 1.7950x; 1.1186x over previous
//
#include <hip/hip_runtime.h>
#include <hip/hip_bf16.h>
#include <math.h>

#define NB 32768      // total nodes (B*N)
#define NN 2048       // nodes per graph
#define BG 16         // graphs
#define KK 1639       // kept per graph
#define N1 (BG*KK)    // 26224 kept nodes total
#define EE 524288     // total edges
#define HH 128        // hidden
#define FIN 64        // input features
#define SLICES 16

using half8 = __attribute__((ext_vector_type(8))) _Float16;
using f32x4 = __attribute__((ext_vector_type(4))) float;

// ---------------- CSR build ----------------
__global__ void deg_kernel(const int* __restrict__ dst, int* deg, int n) {
  int e = blockIdx.x * blockDim.x + threadIdx.x;
  if (e < n) atomicAdd(&deg[dst[e]], 1);
}

__global__ void deg2_kernel(const int* __restrict__ src, const int* __restrict__ dst,
                            const int* __restrict__ new_id, int* deg, int n) {
  int e = blockIdx.x * blockDim.x + threadIdx.x;
  if (e < n) {
    int a = new_id[src[e]], d = new_id[dst[e]];
    if (a >= 0 && d >= 0) atomicAdd(&deg[d], 1);
  }
}

// single-block coalesced exclusive scan over tiles of 4096 (int4/lane);
// writes rs[0..n] and cursor[0..n-1]. Caller must pad deg so int4 reads up to
// ceil(n/4096)*4096 stay in-bounds.
__global__ void exscan_kernel(const int* __restrict__ deg, int* rs, int* cursor, int n) {
  __shared__ int wsum[16];
  __shared__ int carry;
  int t = threadIdx.x;  // 1024
  int lane = t & 63, wid = t >> 6;
  if (t == 0) carry = 0;
  __syncthreads();
  int ntiles = (n + 4095) >> 12;
  for (int tile = 0; tile < ntiles; ++tile) {
    int idx = (tile << 12) + t * 4;
    int4 v4 = *(const int4*)(deg + idx);  // coalesced 16B/lane (padded alloc)
    int v0 = (idx + 0 < n) ? v4.x : 0;
    int v1 = (idx + 1 < n) ? v4.y : 0;
    int v2 = (idx + 2 < n) ? v4.z : 0;
    int v3 = (idx + 3 < n) ? v4.w : 0;
    int s = v0 + v1 + v2 + v3;
    int pre = s;
#pragma unroll
    for (int off = 1; off < 64; off <<= 1) {
      int u = __shfl_up(pre, off, 64);
      if (lane >= off) pre += u;
    }
    if (lane == 63) wsum[wid] = pre;
    __syncthreads();
    int wbase = 0;
#pragma unroll
    for (int ww = 0; ww < 16; ++ww)
      if (ww < wid) wbase += wsum[ww];
    int ex = carry + wbase + (pre - s);
    int4 e4 = make_int4(ex, ex + v0, ex + v0 + v1, ex + v0 + v1 + v2);
    if (idx + 3 < n) {
      *(int4*)(rs + idx) = e4;
      *(int4*)(cursor + idx) = e4;
    } else {
      if (idx + 0 < n) { rs[idx + 0] = e4.x; cursor[idx + 0] = e4.x; }
      if (idx + 1 < n) { rs[idx + 1] = e4.y; cursor[idx + 1] = e4.y; }
      if (idx + 2 < n) { rs[idx + 2] = e4.z; cursor[idx + 2] = e4.z; }
    }
    int tot = 0;
    if (t == 1023) tot = ex + s;
    __syncthreads();            // all carry-reads done before update
    if (t == 1023) carry = tot;
    __syncthreads();
  }
  if (t == 0) rs[n] = carry;
}

__global__ void scatter_kernel(const int* __restrict__ src, const int* __restrict__ dst,
                               int* cursor, int* csr, int n) {
  int e = blockIdx.x * blockDim.x + threadIdx.x;
  if (e < n) {
    int d = dst[e];
    int p = atomicAdd(&cursor[d], 1);
    csr[p] = src[e];
  }
}

__global__ void scatter2_kernel(const int* __restrict__ src, const int* __restrict__ dst,
                                const int* __restrict__ new_id, int* cursor, int* csr, int n) {
  int e = blockIdx.x * blockDim.x + threadIdx.x;
  if (e < n) {
    int a = new_id[src[e]], d = new_id[dst[e]];
    if (a >= 0 && d >= 0) {
      int p = atomicAdd(&cursor[d], 1);
      csr[p] = a;
    }
  }
}

// ---------------- aggregation (gather-sum, float4, XCD-swizzled, 4-way ILP) ----------------
// block = 256 threads = 4 waves; each wave handles one node; F4 = feature width / 4
template <int F4>
__global__ void agg_kernel(const float4* __restrict__ feat, const int* __restrict__ rs,
                           const int* __restrict__ csr, float4* __restrict__ agg, int M,
                           int nwg) {
  // bijective XCD-chunk swizzle (m204): XCD x gets a contiguous chunk of node space
  int b = blockIdx.x;
  int q = nwg >> 3, r = nwg & 7, x = b & 7, i = b >> 3;
  int swz = (x < r ? x * (q + 1) : r * (q + 1) + (x - r) * q) + i;
  int node = swz * 4 + (threadIdx.x >> 6);
  if (node >= M) return;
  int lane = threadIdx.x & 63;
  constexpr int STEP = 64 / F4;
  int sub = lane / F4, f4 = lane % F4;  // STEP edges in flight per wave
  int e0 = rs[node], e1 = rs[node + 1];
  float4 a0 = make_float4(0.f, 0.f, 0.f, 0.f), a1 = a0, a2 = a0, a3 = a0;
  int e = e0 + sub;
  // 4-way unroll: 4 independent gather chains per lane (latency hiding)
  for (; e + 3 * STEP < e1; e += 4 * STEP) {
    int c0 = csr[e], c1 = csr[e + STEP], c2 = csr[e + 2 * STEP], c3 = csr[e + 3 * STEP];
    float4 v0 = feat[(size_t)c0 * F4 + f4];
    float4 v1 = feat[(size_t)c1 * F4 + f4];
    float4 v2 = feat[(size_t)c2 * F4 + f4];
    float4 v3 = feat[(size_t)c3 * F4 + f4];
    a0.x += v0.x; a0.y += v0.y; a0.z += v0.z; a0.w += v0.w;
    a1.x += v1.x; a1.y += v1.y; a1.z += v1.z; a1.w += v1.w;
    a2.x += v2.x; a2.y += v2.y; a2.z += v2.z; a2.w += v2.w;
    a3.x += v3.x; a3.y += v3.y; a3.z += v3.z; a3.w += v3.w;
  }
  for (; e < e1; e += STEP) {
    float4 v = feat[(size_t)csr[e] * F4 + f4];
    a0.x += v.x; a0.y += v.y; a0.z += v.z; a0.w += v.w;
  }
  float4 acc;
  acc.x = (a0.x + a1.x) + (a2.x + a3.x);
  acc.y = (a0.y + a1.y) + (a2.y + a3.y);
  acc.z = (a0.z + a1.z) + (a2.z + a3.z);
  acc.w = (a0.w + a1.w) + (a2.w + a3.w);
  // reduce partial sums across subs (valid in lanes with sub==0)
  acc.x += __shfl_down(acc.x, 32, 64);
  acc.y += __shfl_down(acc.y, 32, 64);
  acc.z += __shfl_down(acc.z, 32, 64);
  acc.w += __shfl_down(acc.w, 32, 64);
  if (F4 == 16) {
    acc.x += __shfl_down(acc.x, 16, 64);
    acc.y += __shfl_down(acc.y, 16, 64);
    acc.z += __shfl_down(acc.z, 16, 64);
    acc.w += __shfl_down(acc.w, 16, 64);
  }
  if (sub == 0) agg[(size_t)node * F4 + f4] = acc;
}

// ---------------- fused conv GEMM via f16 split-precision MFMA ----------------
// out = relu([agg|x] @ Wcat^T + b); Wcat pre-split into Wh + Wl (f16), [128][KTOT].
// Block: 512 thr = 8 waves; block tile = 64 rows x 128 cols; wave = 64x16 (4 row-frags).
// W register-stationary (full K) -> zero B loads in k-loop; W L2 traffic /4 vs 16-row tile.
// A staged once to LDS (f16 hi/lo planes, XOR-swizzled); k-loop = ds_read + MFMA only.
template <int KD1, int KD2>
__global__ __launch_bounds__(512) void conv_mfma(
    const float* __restrict__ agg, const float* __restrict__ xr,
    const _Float16* __restrict__ Wh, const _Float16* __restrict__ Wl,
    const float* __restrict__ bias, float* __restrict__ out, int M) {
  constexpr int KTOT = KD1 + KD2;
  constexpr int NSTEP = KTOT / 32;
  __shared__ _Float16 ah_lds[64 * KTOT];
  __shared__ _Float16 al_lds[64 * KTOT];

  int tid = threadIdx.x;
  int lane = tid & 63, wid = tid >> 6;
  int row0 = blockIdx.x * 64;
  int ch0 = wid * 16;           // 8 waves cover the 128 output cols
  int col = lane & 15;
  int kseg = (lane >> 4) * 8;

  // ---- W preload: full-K B fragments into registers (static indexing) ----
  half8 wh_r[NSTEP], wl_r[NSTEP];
#pragma unroll
  for (int s = 0; s < NSTEP; ++s) {
    size_t wof = (size_t)(ch0 + col) * KTOT + s * 32 + kseg;
    wh_r[s] = *(const half8*)(Wh + wof);
    wl_r[s] = *(const half8*)(Wl + wof);
  }

  // ---- stage A panel: 64 rows x KTOT f32 -> hi/lo f16 LDS planes ----
  for (int idx = tid; idx < 64 * KTOT / 8; idx += 512) {
    int row = idx / (KTOT / 8);
    int kc = (idx % (KTOT / 8)) * 8;  // 8-elem chunk, never crosses KD1 (both %64==0)
    int grow = row0 + row;
    if (grow >= M) grow = M - 1;  // clamp (tail block); stores are guarded
    const float* sp = (kc < KD1) ? (agg + (size_t)grow * KD1 + kc)
                                 : (xr + (size_t)grow * KD2 + (kc - KD1));
    float4 a0 = *(const float4*)sp;
    float4 a1 = *(const float4*)(sp + 4);
    float av[8] = {a0.x, a0.y, a0.z, a0.w, a1.x, a1.y, a1.z, a1.w};
    half8 vh, vl;
#pragma unroll
    for (int j = 0; j < 8; ++j) {
      _Float16 h = (_Float16)av[j];
      vh[j] = h;
      vl[j] = (_Float16)(av[j] - (float)h);
    }
    int byte = ((row * KTOT + kc) * 2) ^ ((row & 7) << 4);
    *(half8*)((char*)ah_lds + byte) = vh;
    *(half8*)((char*)al_lds + byte) = vl;
  }
  __syncthreads();

  // ---- k-loop: pure ds_read + MFMA; per step: 8 ds_read_b128 + 12 MFMA ----
  f32x4 acc[4];
#pragma unroll
  for (int rf = 0; rf < 4; ++rf) acc[rf] = (f32x4){0.f, 0.f, 0.f, 0.f};
  int r = lane & 15;
#pragma unroll
  for (int s = 0; s < NSTEP; ++s) {
#pragma unroll
    for (int rf = 0; rf < 4; ++rf) {
      int row = rf * 16 + r;
      int byte = ((row * KTOT + s * 32 + kseg) * 2) ^ ((row & 7) << 4);
      half8 a_h = *(const half8*)((const char*)ah_lds + byte);
      half8 a_l = *(const half8*)((const char*)al_lds + byte);
      acc[rf] = __builtin_amdgcn_mfma_f32_16x16x32_f16(a_l, wh_r[s], acc[rf], 0, 0, 0);
      acc[rf] = __builtin_amdgcn_mfma_f32_16x16x32_f16(a_h, wl_r[s], acc[rf], 0, 0, 0);
      acc[rf] = __builtin_amdgcn_mfma_f32_16x16x32_f16(a_h, wh_r[s], acc[rf], 0, 0, 0);
    }
  }

  // ---- epilogue: bias + relu; C/D map col=lane&15, row=(lane>>4)*4+reg ----
  float bv = bias[ch0 + col];
#pragma unroll
  for (int rf = 0; rf < 4; ++rf) {
    int orow0 = row0 + rf * 16 + (lane >> 4) * 4;
#pragma unroll
    for (int rr = 0; rr < 4; ++rr) {
      int orow = orow0 + rr;
      if (orow < M) out[(size_t)orow * HH + ch0 + col] = fmaxf(acc[rf][rr] + bv, 0.f);
    }
  }
}

// ---------------- weight prep: split Wcat[o][k] into f16 hi + lo planes ----------------
__global__ void prep_weights_f16(const float* __restrict__ W1_rel, const float* __restrict__ W1_root,
                                 const float* __restrict__ W2_rel, const float* __restrict__ W2_root,
                                 const float* __restrict__ W3_rel, const float* __restrict__ W3_root,
                                 _Float16* wh1, _Float16* wl1, _Float16* wh2, _Float16* wl2,
                                 _Float16* wh3, _Float16* wl3) {
  int idx = blockIdx.x * blockDim.x + threadIdx.x;
  float v;
  _Float16* ph;
  _Float16* pl;
  int j;
  if (idx < 128 * 128) {
    j = idx;
    int o = j >> 7, k = j & 127;
    v = (k < 64) ? W1_rel[o * 64 + k] : W1_root[o * 64 + (k - 64)];
    ph = wh1; pl = wl1;
  } else if (idx < 128 * 128 + 128 * 256) {
    j = idx - 128 * 128;
    int o = j >> 8, k = j & 255;
    v = (k < 128) ? W2_rel[o * 128 + k] : W2_root[o * 128 + (k - 128)];
    ph = wh2; pl = wl2;
  } else if (idx < 128 * 128 + 2 * 128 * 256) {
    j = idx - 128 * 128 - 128 * 256;
    int o = j >> 8, k = j & 255;
    v = (k < 128) ? W3_rel[o * 128 + k] : W3_root[o * 128 + (k - 128)];
    ph = wh3; pl = wl3;
  } else {
    return;
  }
  _Float16 h = (_Float16)v;
  ph[j] = h;
  pl[j] = (_Float16)(v - (float)h);
}

// ---------------- pooling partials ----------------
__global__ void pool_partial_kernel(const float* __restrict__ h, int rows_per_graph,
                                    float* pmax, float* psum) {
  int b = blockIdx.x / SLICES, s = blockIdx.x % SLICES;
  int f = threadIdx.x;
  int per = (rows_per_graph + SLICES - 1) / SLICES;
  int r0 = s * per, r1 = min(rows_per_graph, r0 + per);
  float m = -3.402823466e38f, sum = 0.f;
  for (int r = r0; r < r1; ++r) {
    float v = h[(size_t)(b * rows_per_graph + r) * HH + f];
    m = fmaxf(m, v);
    sum += v;
  }
  pmax[(b * SLICES + s) * HH + f] = m;
  psum[(b * SLICES + s) * HH + f] = sum;
}

// ---------------- scoring (norm fused per-wave) ----------------
__global__ void score_kernel(const float* __restrict__ h2, const float* __restrict__ w,
                             float* score, int M) {
  int wave = threadIdx.x >> 6;
  int lane = threadIdx.x & 63;
  int i = blockIdx.x * (blockDim.x >> 6) + wave;
  if (i >= M) return;
  float wl0 = w[lane], wl1 = w[64 + lane];
  float acc = h2[i * HH + lane] * wl0 + h2[i * HH + 64 + lane] * wl1;
  float nsq = wl0 * wl0 + wl1 * wl1;
  for (int off = 32; off > 0; off >>= 1) {
    acc += __shfl_down(acc, off, 64);
    nsq += __shfl_down(nsq, off, 64);
  }
  if (lane == 0) score[i] = tanhf(acc / sqrtf(nsq));
}

// per-graph bitonic sort of 2048 (score,index) keys; keep top K, tie-break lowest index
__global__ void topk_kernel(const float* __restrict__ score, int* perm) {
  __shared__ unsigned long long k[NN];
  int b = blockIdx.x;
  int tid = threadIdx.x;  // 1024
  for (int i = tid; i < NN; i += 1024) {
    float s = score[b * NN + i];
    unsigned u = __float_as_uint(s);
    u = (u & 0x80000000u) ? ~u : (u | 0x80000000u);
    unsigned long long key = ((unsigned long long)u << 32) | (unsigned)(NN - 1 - i);
    k[i] = ~key;  // ascending sort of ~key == descending by (score, -index)
  }
  __syncthreads();
  for (int kk = 2; kk <= NN; kk <<= 1) {
    for (int j = kk >> 1; j > 0; j >>= 1) {
      for (int t = tid; t < NN; t += 1024) {
        int ixj = t ^ j;
        if (ixj > t) {
          bool up = ((t & kk) == 0);
          unsigned long long a = k[t], c = k[ixj];
          if ((a > c) == up) { k[t] = c; k[ixj] = a; }
        }
      }
      __syncthreads();
    }
  }
  for (int j = tid; j < KK; j += 1024) {
    unsigned long long key = ~k[j];
    int i = (NN - 1) - (int)(key & 0xffffffffu);
    perm[b * KK + j] = b * NN + i;
  }
}

// gather kept rows, scale by score, and write new_id (fused)
__global__ void h3_kernel(const float4* __restrict__ h2, const int* __restrict__ perm,
                          const float* __restrict__ score, float4* __restrict__ h3,
                          int* new_id) {
  int idx = blockIdx.x * blockDim.x + threadIdx.x;  // over N1*32 float4s
  if (idx < N1 * 32) {
    int g = idx >> 5, c = idx & 31;
    int p = perm[g];
    if (c == 0) new_id[p] = g;
    float s = score[p];
    float4 v = h2[(size_t)p * 32 + c];
    v.x *= s; v.y *= s; v.z *= s; v.w *= s;
    h3[idx] = v;
  }
}

// ---------------- final: pool-final x3 + MLP + log_softmax ----------------
__global__ void mlp_kernel(const float* __restrict__ pm1, const float* __restrict__ ps1,
                           const float* __restrict__ pm2, const float* __restrict__ ps2,
                           const float* __restrict__ pm3, const float* __restrict__ ps3,
                           const float* __restrict__ Wl1, const float* __restrict__ bl1,
                           const float* __restrict__ Wl2, const float* __restrict__ bl2,
                           const float* __restrict__ Wl3, const float* __restrict__ bl3,
                           float* out) {
  __shared__ float z[256], a1[128], a2[64], a3[10], red[2];
  int b = blockIdx.x, t = threadIdx.x;  // 128 threads
  float m1 = -3.402823466e38f, m2 = m1, m3 = m1;
  float s1 = 0.f, s2 = 0.f, s3 = 0.f;
  for (int s = 0; s < SLICES; ++s) {
    int o = (b * SLICES + s) * 128 + t;
    m1 = fmaxf(m1, pm1[o]); s1 += ps1[o];
    m2 = fmaxf(m2, pm2[o]); s2 += ps2[o];
    m3 = fmaxf(m3, pm3[o]); s3 += ps3[o];
  }
  z[t] = m1 + m2 + m3;
  z[128 + t] = s1 * (1.f / NN) + (s2 + s3) * (1.f / KK);
  __syncthreads();
  {
    float acc = bl1[t];
    for (int q = 0; q < 256; ++q) acc = fmaf(Wl1[t * 256 + q], z[q], acc);
    a1[t] = fmaxf(acc, 0.f);
  }
  __syncthreads();
  if (t < 64) {
    float acc = bl2[t];
    for (int q = 0; q < 128; ++q) acc = fmaf(Wl2[t * 128 + q], a1[q], acc);
    a2[t] = fmaxf(acc, 0.f);
  }
  __syncthreads();
  if (t < 10) {
    float acc = bl3[t];
    for (int q = 0; q < 64; ++q) acc = fmaf(Wl3[t * 64 + q], a2[q], acc);
    a3[t] = acc;
  }
  __syncthreads();
  if (t == 0) {
    float m = a3[0];
    for (int i = 1; i < 10; ++i) m = fmaxf(m, a3[i]);
    float s = 0.f;
    for (int i = 0; i < 10; ++i) s += expf(a3[i] - m);
    red[0] = m;
    red[1] = logf(s);
  }
  __syncthreads();
  if (t < 10) out[b * 10 + t] = a3[t] - red[0] - red[1];
}

extern "C" void kernel_launch(void* const* d_in, const int* in_sizes, int n_in,
                              void* d_out, int out_size, void* d_ws, size_t ws_size,
                              hipStream_t stream) {
  const float* x       = (const float*)d_in[0];
  const int*   src     = (const int*)d_in[1];
  const int*   dst     = (const int*)d_in[2];
  const float* W1_rel  = (const float*)d_in[3];
  const float* b1      = (const float*)d_in[4];
  const float* W1_root = (const float*)d_in[5];
  const float* W2_rel  = (const float*)d_in[6];
  const float* b2      = (const float*)d_in[7];
  const float* W2_root = (const float*)d_in[8];
  const float* W3_rel  = (const float*)d_in[9];
  const float* b3      = (const float*)d_in[10];
  const float* W3_root = (const float*)d_in[11];
  const float* pool_w  = (const float*)d_in[12];
  const float* Wl1     = (const float*)d_in[13];
  const float* bl1     = (const float*)d_in[14];
  const float* Wl2     = (const float*)d_in[15];
  const float* bl2     = (const float*)d_in[16];
  const float* Wl3     = (const float*)d_in[17];
  const float* bl3     = (const float*)d_in[18];
  float* out = (float*)d_out;

  // workspace layout
  char* w = (char*)d_ws;
  size_t off = 0;
  auto alloc = [&](size_t bytes) -> char* {
    off = (off + 255) & ~(size_t)255;
    char* p = w + off;
    off += bytes;
    return p;
  };
  // deg1 | deg2 contiguous (one memset); +4096 ints pad for exscan int4 tiles
  int* degs     = (int*)alloc((NB + N1 + 4096) * 4);
  int* deg1     = degs;
  int* deg2     = degs + NB;
  int* rs1      = (int*)alloc((NB + 1) * 4);
  int* cursor1  = (int*)alloc(NB * 4);
  int* csr1     = (int*)alloc((size_t)EE * 4);
  int* rs2      = (int*)alloc((N1 + 1) * 4);
  int* cursor2  = (int*)alloc(N1 * 4);
  int* csr2     = (int*)alloc((size_t)EE * 4);
  int* new_id   = (int*)alloc(NB * 4);
  int* perm     = (int*)alloc(N1 * 4);
  _Float16* wh1 = (_Float16*)alloc(128 * 128 * 2);
  _Float16* wl1 = (_Float16*)alloc(128 * 128 * 2);
  _Float16* wh2 = (_Float16*)alloc(128 * 256 * 2);
  _Float16* wl2 = (_Float16*)alloc(128 * 256 * 2);
  _Float16* wh3 = (_Float16*)alloc(128 * 256 * 2);
  _Float16* wl3 = (_Float16*)alloc(128 * 256 * 2);
  float* aggbuf = (float*)alloc((size_t)NB * HH * 4);
  float* bufA   = (float*)alloc((size_t)NB * HH * 4);  // h1, then h3
  float* bufB   = (float*)alloc((size_t)NB * HH * 4);  // h2, then h4
  float* score  = (float*)alloc(NB * 4);
  float* pm1    = (float*)alloc(BG * SLICES * HH * 4);
  float* ps1    = (float*)alloc(BG * SLICES * HH * 4);
  float* pm2    = (float*)alloc(BG * SLICES * HH * 4);
  float* ps2    = (float*)alloc(BG * SLICES * HH * 4);
  float* pm3    = (float*)alloc(BG * SLICES * HH * 4);
  float* ps3    = (float*)alloc(BG * SLICES * HH * 4);
  if (off > ws_size) return;  // workspace too small: fail visibly

  const int TB = 256;
  const int egrid = (EE + TB - 1) / TB;

  hipMemsetAsync(degs, 0, (NB + N1 + 4096) * 4, stream);
  hipMemsetAsync(new_id, 0xFF, NB * 4, stream);  // -1

  prep_weights_f16<<<(128 * 128 + 2 * 128 * 256 + TB - 1) / TB, TB, 0, stream>>>(
      W1_rel, W1_root, W2_rel, W2_root, W3_rel, W3_root, wh1, wl1, wh2, wl2, wh3, wl3);

  // CSR1 (src -> dst)
  deg_kernel<<<egrid, TB, 0, stream>>>(dst, deg1, EE);
  exscan_kernel<<<1, 1024, 0, stream>>>(deg1, rs1, cursor1, NB);
  scatter_kernel<<<egrid, TB, 0, stream>>>(src, dst, cursor1, csr1, EE);

  // conv1 (K = 64 agg + 64 root)
  agg_kernel<16><<<NB / 4, 256, 0, stream>>>((const float4*)x, rs1, csr1, (float4*)aggbuf,
                                             NB, NB / 4);
  conv_mfma<64, 64><<<NB / 64, 512, 0, stream>>>(aggbuf, x, wh1, wl1, b1, bufA, NB);
  pool_partial_kernel<<<BG * SLICES, 128, 0, stream>>>(bufA, NN, pm1, ps1);

  // conv2
  agg_kernel<32><<<NB / 4, 256, 0, stream>>>((const float4*)bufA, rs1, csr1, (float4*)aggbuf,
                                             NB, NB / 4);
  conv_mfma<128, 128><<<NB / 64, 512, 0, stream>>>(aggbuf, bufA, wh2, wl2, b2, bufB, NB);

  // topk
  score_kernel<<<NB / 4, 256, 0, stream>>>(bufB, pool_w, score, NB);
  topk_kernel<<<BG, 1024, 0, stream>>>(score, perm);
  h3_kernel<<<(N1 * 32 + TB - 1) / TB, TB, 0, stream>>>((const float4*)bufB, perm, score,
                                                        (float4*)bufA, new_id);
  pool_partial_kernel<<<BG * SLICES, 128, 0, stream>>>(bufA, KK, pm2, ps2);

  // CSR2 over remapped kept edges
  deg2_kernel<<<egrid, TB, 0, stream>>>(src, dst, new_id, deg2, EE);
  exscan_kernel<<<1, 1024, 0, stream>>>(deg2, rs2, cursor2, N1);
  scatter2_kernel<<<egrid, TB, 0, stream>>>(src, dst, new_id, cursor2, csr2, EE);

  // conv3
  agg_kernel<32><<<(N1 + 3) / 4, 256, 0, stream>>>((const float4*)bufA, rs2, csr2,
                                                   (float4*)aggbuf, N1, (N1 + 3) / 4);
  conv_mfma<128, 128><<<(N1 + 63) / 64, 512, 0, stream>>>(aggbuf, bufA, wh3, wl3, b3, bufB,
                                                          N1);
  pool_partial_kernel<<<BG * SLICES, 128, 0, stream>>>(bufB, KK, pm3, ps3);

  // pool finals + MLP head + log_softmax (fused)
  mlp_kernel<<<BG, 128, 0, stream>>>(pm1, ps1, pm2, ps2, pm3, ps3,
                                     Wl1, bl1, Wl2, bl2, Wl3, bl3, out);
}